// Round 2
// baseline (11197.088 us; speedup 1.0000x reference)
//
#include <hip/hip_runtime.h>

// ---------------------------------------------------------------------------
// VIN on MI355X. B=128, H=W=64. Channels 2 -> 150 -> 120 -> 100, q=10, K=36.
// Workspace-lean plan (~220 MiB peak):
//   conv1: stats-only pass (no store); conv1+BN1+ReLU recomputed inside
//          conv2's LDS staging (conv1 is 2-channel -> trivial flops).
//   t2 = conv2 raw output (+bias) stored bf16 [128,120,64,64]  (126 MB)
//   t3 = conv3 raw output (+bias) stored bf16 [128,100,64,64]  (105 MB)
//   BN2 fused into conv3 staging; BN3+ReLU+1x1 reward reduce fused.
//   VI loop (qr, v ping-pong) in fp32, aliased over dead t2 region.
// ---------------------------------------------------------------------------

#define NHW 524288.0f   // 128*4096

static __device__ __forceinline__ float bf2f(unsigned short u) {
  return __uint_as_float(((unsigned int)u) << 16);
}
static __device__ __forceinline__ unsigned short f2bf(float f) {
  unsigned int x = __float_as_uint(f);
  return (unsigned short)((x + 0x7fffu + ((x >> 16) & 1u)) >> 16);  // RNE
}
static __device__ __forceinline__ float wave_sum(float s) {
  #pragma unroll
  for (int off = 32; off > 0; off >>= 1) s += __shfl_down(s, off, 64);
  return s;
}

// ---------------- conv1 (2->150) stats-only: sum & sumsq of conv+bias ------
__global__ __launch_bounds__(256) void conv1_stats(
    const float* __restrict__ X, const float* __restrict__ w1,
    const float* __restrict__ b1, float* __restrict__ S, float* __restrict__ Q)
{
  const int tile = blockIdx.x;             // 128*8
  const int b    = tile >> 3;
  const int y0t  = (tile & 7) * 8;
  const int co0  = blockIdx.y * 15;        // 10 groups of 15
  const int tid  = threadIdx.x;
  const int x    = tid & 63;
  const int ly0  = (tid >> 6) * 2;

  __shared__ float lin[2][10][66];
  for (int idx = tid; idx < 2 * 10 * 66; idx += 256) {
    int cc = idx / 660, rem = idx - cc * 660;
    int rr = rem / 66,  c   = rem - rr * 66;
    int yy = y0t + rr - 1, xx = c - 1;
    lin[cc][rr][c] = (yy >= 0 && yy < 64 && xx >= 0 && xx < 64)
                         ? X[((size_t)(b * 2 + cc) << 12) + (yy << 6) + xx] : 0.f;
  }
  __syncthreads();

  float iv[2][4][3];
  #pragma unroll
  for (int cc = 0; cc < 2; cc++)
    #pragma unroll
    for (int r = 0; r < 4; r++)
      #pragma unroll
      for (int c = 0; c < 3; c++) iv[cc][r][c] = lin[cc][ly0 + r][x + c];

  #pragma unroll
  for (int co = 0; co < 15; co++) {
    const float* w9 = w1 + (size_t)(co0 + co) * 18;
    float a0 = 0.f, a1 = 0.f;
    #pragma unroll
    for (int cc = 0; cc < 2; cc++)
      #pragma unroll
      for (int ky = 0; ky < 3; ky++)
        #pragma unroll
        for (int kx = 0; kx < 3; kx++) {
          float wv = w9[cc * 9 + ky * 3 + kx];
          a0 = fmaf(iv[cc][ky][kx],     wv, a0);
          a1 = fmaf(iv[cc][ky + 1][kx], wv, a1);
        }
    float bz = b1[co0 + co];
    float t0 = a0 + bz, t1 = a1 + bz;
    float s  = wave_sum(t0 + t1);
    float q  = wave_sum(t0 * t0 + t1 * t1);
    if ((tid & 63) == 0) {
      atomicAdd(&S[co0 + co], s);
      atomicAdd(&Q[co0 + co], q);
    }
  }
}

// ---------------- BN finalize: A = g*rsqrt(var+eps), B = beta - mean*A -----
template <int C>
__global__ void bn_finalize(const float* __restrict__ S, const float* __restrict__ Q,
                            const float* __restrict__ g, const float* __restrict__ be,
                            float* __restrict__ A, float* __restrict__ Bs)
{
  int c = threadIdx.x;
  if (c < C) {
    const float invN = 1.f / NHW;
    float m   = S[c] * invN;
    float var = fmaxf(Q[c] * invN - m * m, 0.f);
    float sc  = g[c] * rsqrtf(var + 1e-5f);
    A[c]  = sc;
    Bs[c] = be[c] - m * sc;
  }
}

// ---------------- fused conv2: (conv1+BN1+ReLU on the fly) -> conv2+bias ---
// block = 1024 threads, tile 64x4 px, all 120 output channels (30 per group).
__global__ __launch_bounds__(1024, 4) void conv2_fused(
    const float* __restrict__ X,  const float* __restrict__ w1,
    const float* __restrict__ b1, const float* __restrict__ A1,
    const float* __restrict__ B1, const float* __restrict__ w2,
    const float* __restrict__ b2, unsigned short* __restrict__ t2)
{
  const int tile = blockIdx.x;           // 128*16
  const int b    = tile >> 4;
  const int y0t  = (tile & 15) * 4;
  const int tid  = threadIdx.x;

  __shared__ float Xs[2][8][68];               // X rows y0t-2..y0t+5, cols -2..65
  __shared__ float w1s[2700];
  __shared__ float A1s[150], B1s[150], b1s[150];
  __shared__ unsigned short h1t[150 * 396];    // [ci][6 rows][66 cols] bf16

  for (int i = tid; i < 2700; i += 1024) w1s[i] = w1[i];
  for (int i = tid; i < 150; i += 1024) { A1s[i] = A1[i]; B1s[i] = B1[i]; b1s[i] = b1[i]; }
  for (int i = tid; i < 2 * 8 * 68; i += 1024) {
    int cc = i / 544, rem = i - cc * 544;
    int rr = rem / 68, c = rem - rr * 68;
    int yy = y0t - 2 + rr, xx = c - 2;
    Xs[cc][rr][c] = (yy >= 0 && yy < 64 && xx >= 0 && xx < 64)
                        ? X[((size_t)(b * 2 + cc) << 12) + (yy << 6) + xx] : 0.f;
  }
  __syncthreads();

  // h1 tile: rows y0t-1..y0t+4 (rr 0..5), cols -1..64 (cc 0..65)
  for (int i = tid; i < 150 * 396; i += 1024) {
    int ci = i / 396, rem = i - ci * 396;
    int rr = rem / 66, cc = rem - rr * 66;
    int gy = y0t - 1 + rr, gx = cc - 1;
    float v = 0.f;
    if (gy >= 0 && gy < 64 && gx >= 0 && gx < 64) {
      float acc = b1s[ci];
      #pragma unroll
      for (int c2 = 0; c2 < 2; c2++)
        #pragma unroll
        for (int ky = 0; ky < 3; ky++)
          #pragma unroll
          for (int kx = 0; kx < 3; kx++)
            acc = fmaf(Xs[c2][rr + ky][cc + kx], w1s[(ci * 2 + c2) * 9 + ky * 3 + kx], acc);
      v = fmaxf(fmaf(acc, A1s[ci], B1s[ci]), 0.f);
    }
    h1t[i] = f2bf(v);
  }
  __syncthreads();

  const int g  = __builtin_amdgcn_readfirstlane(tid >> 8);   // 0..3 -> 30 co each
  const int x  = tid & 63;
  const int ly = (tid >> 6) & 3;

  float acc[30];
  #pragma unroll
  for (int i = 0; i < 30; i++) acc[i] = 0.f;

  for (int ci = 0; ci < 150; ci++) {
    float iv[3][3];
    const unsigned short* hp = &h1t[ci * 396 + ly * 66 + x];
    #pragma unroll
    for (int ky = 0; ky < 3; ky++)
      #pragma unroll
      for (int kx = 0; kx < 3; kx++) iv[ky][kx] = bf2f(hp[ky * 66 + kx]);

    const float* wp = w2 + (size_t)g * 40500 + (size_t)ci * 9;
    #pragma unroll
    for (int co = 0; co < 30; co++) {
      const float* w9 = wp + (size_t)co * 1350;
      #pragma unroll
      for (int ky = 0; ky < 3; ky++)
        #pragma unroll
        for (int kx = 0; kx < 3; kx++)
          acc[co] = fmaf(iv[ky][kx], w9[ky * 3 + kx], acc[co]);
    }
  }

  const int y = y0t + ly;
  #pragma unroll
  for (int co = 0; co < 30; co++) {
    int coi = g * 30 + co;
    t2[((size_t)(b * 120 + coi) << 12) + (y << 6) + x] = f2bf(acc[co] + b2[coi]);
  }
}

// ---------------- fused conv3: (BN2+ReLU on staged t2) -> conv3+bias -------
__global__ __launch_bounds__(1024, 4) void conv3_fused(
    const unsigned short* __restrict__ t2, const float* __restrict__ A2,
    const float* __restrict__ B2, const float* __restrict__ w3,
    const float* __restrict__ b3, unsigned short* __restrict__ t3)
{
  const int tile = blockIdx.x;
  const int b    = tile >> 4;
  const int y0t  = (tile & 15) * 4;
  const int tid  = threadIdx.x;

  __shared__ unsigned short h2t[120 * 396];    // bf16 [ci][6][66]
  __shared__ float A2s[120], B2s[120];

  for (int i = tid; i < 120; i += 1024) { A2s[i] = A2[i]; B2s[i] = B2[i]; }
  __syncthreads();

  for (int i = tid; i < 120 * 396; i += 1024) {
    int ci = i / 396, rem = i - ci * 396;
    int rr = rem / 66, cc = rem - rr * 66;
    int gy = y0t - 1 + rr, gx = cc - 1;
    float v = 0.f;
    if (gy >= 0 && gy < 64 && gx >= 0 && gx < 64) {
      float raw = bf2f(t2[((size_t)(b * 120 + ci) << 12) + (gy << 6) + gx]);
      v = fmaxf(fmaf(raw, A2s[ci], B2s[ci]), 0.f);
    }
    h2t[i] = f2bf(v);
  }
  __syncthreads();

  const int g  = __builtin_amdgcn_readfirstlane(tid >> 8);   // 0..3 -> 25 co each
  const int x  = tid & 63;
  const int ly = (tid >> 6) & 3;

  float acc[25];
  #pragma unroll
  for (int i = 0; i < 25; i++) acc[i] = 0.f;

  for (int ci = 0; ci < 120; ci++) {
    float iv[3][3];
    const unsigned short* hp = &h2t[ci * 396 + ly * 66 + x];
    #pragma unroll
    for (int ky = 0; ky < 3; ky++)
      #pragma unroll
      for (int kx = 0; kx < 3; kx++) iv[ky][kx] = bf2f(hp[ky * 66 + kx]);

    const float* wp = w3 + (size_t)(g * 25) * 1080 + (size_t)ci * 9;
    #pragma unroll
    for (int co = 0; co < 25; co++) {
      const float* w9 = wp + (size_t)co * 1080;
      #pragma unroll
      for (int ky = 0; ky < 3; ky++)
        #pragma unroll
        for (int kx = 0; kx < 3; kx++)
          acc[co] = fmaf(iv[ky][kx], w9[ky * 3 + kx], acc[co]);
    }
  }

  const int y = y0t + ly;
  #pragma unroll
  for (int co = 0; co < 25; co++) {
    int coi = g * 25 + co;
    t3[((size_t)(b * 100 + coi) << 12) + (y << 6) + x] = f2bf(acc[co] + b3[coi]);
  }
}

// ---------------- BN stats over a bf16 tensor ------------------------------
template <int C>
__global__ __launch_bounds__(256) void bn_stats_bf16(
    const unsigned short* __restrict__ t, float* __restrict__ S, float* __restrict__ Q)
{
  const int c  = blockIdx.x;
  const int b0 = blockIdx.y * 4;
  const int tid = threadIdx.x;
  float s = 0.f, s2 = 0.f;
  for (int bb = 0; bb < 4; bb++) {
    const ushort4* p = (const ushort4*)(t + (((size_t)(b0 + bb) * C + c) << 12));
    #pragma unroll
    for (int i = 0; i < 4; i++) {
      ushort4 u = p[tid + 256 * i];
      float a = bf2f(u.x), b = bf2f(u.y), cc = bf2f(u.z), d = bf2f(u.w);
      s  += (a + b) + (cc + d);
      s2 += (a * a + b * b) + (cc * cc + d * d);
    }
  }
  s = wave_sum(s); s2 = wave_sum(s2);
  __shared__ float ls[2][4];
  const int w = tid >> 6;
  if ((tid & 63) == 0) { ls[0][w] = s; ls[1][w] = s2; }
  __syncthreads();
  if (tid == 0) {
    atomicAdd(&S[c], ls[0][0] + ls[0][1] + ls[0][2] + ls[0][3]);
    atomicAdd(&Q[c], ls[1][0] + ls[1][1] + ls[1][2] + ls[1][3]);
  }
}

// ---------------- BN3+ReLU+1x1 reward reduce: r = sum_c rw[c]*h3[c] --------
__global__ __launch_bounds__(256) void bn3_reduce_r(
    const unsigned short* __restrict__ t3, const float* __restrict__ A3,
    const float* __restrict__ B3, const float* __restrict__ rw,
    float* __restrict__ r)
{
  const int i  = blockIdx.x * 256 + threadIdx.x;   // 131072 float4-groups
  const int b  = i >> 10;
  const int s4 = i & 1023;
  const unsigned short* base = t3 + (((size_t)b * 100) << 12) + s4 * 4;
  float a0 = 0.f, a1 = 0.f, a2 = 0.f, a3 = 0.f;
  for (int c = 0; c < 100; c++) {
    float sc = A3[c], sh = B3[c], wv = rw[c];
    ushort4 u = *(const ushort4*)(base + ((size_t)c << 12));
    a0 = fmaf(fmaxf(fmaf(bf2f(u.x), sc, sh), 0.f), wv, a0);
    a1 = fmaf(fmaxf(fmaf(bf2f(u.y), sc, sh), 0.f), wv, a1);
    a2 = fmaf(fmaxf(fmaf(bf2f(u.z), sc, sh), 0.f), wv, a2);
    a3 = fmaf(fmaxf(fmaf(bf2f(u.w), sc, sh), 0.f), wv, a3);
  }
  float4 o = {a0, a1, a2, a3};
  ((float4*)r)[i] = o;
}

// ---------------- qr = conv5x5(r, q_w); v0 = max_a qr ----------------------
__global__ __launch_bounds__(256) void qr_init(
    const float* __restrict__ r, const float* __restrict__ qw,
    float* __restrict__ qr, float* __restrict__ v0)
{
  const int tile = blockIdx.x;          // 128*16
  const int b    = tile >> 4;
  const int y0t  = (tile & 15) * 4;
  const int tid  = threadIdx.x;
  const int x    = tid & 63;
  const int ly   = tid >> 6;

  __shared__ float lv[8][68];
  for (int idx = tid; idx < 8 * 68; idx += 256) {
    int rr = idx / 68, c = idx - rr * 68;
    int yy = y0t + rr - 2, xx = c - 2;
    lv[rr][c] = (yy >= 0 && yy < 64 && xx >= 0 && xx < 64)
                    ? r[((size_t)b << 12) + (yy << 6) + xx] : 0.f;
  }
  __syncthreads();

  float iv[5][5];
  #pragma unroll
  for (int ky = 0; ky < 5; ky++)
    #pragma unroll
    for (int kx = 0; kx < 5; kx++) iv[ky][kx] = lv[ly + ky][x + kx];

  const int y = y0t + ly;
  float vmax = -1e30f;
  #pragma unroll
  for (int a = 0; a < 10; a++) {
    float q = 0.f;
    #pragma unroll
    for (int ky = 0; ky < 5; ky++)
      #pragma unroll
      for (int kx = 0; kx < 5; kx++)
        q = fmaf(iv[ky][kx], qw[a * 25 + ky * 5 + kx], q);
    qr[((size_t)(b * 10 + a) << 12) + (y << 6) + x] = q;
    vmax = fmaxf(vmax, q);
  }
  v0[((size_t)b << 12) + (y << 6) + x] = vmax;
}

// ---------------- VI step: v' = max_a (qr + conv5x5(v, w)) -----------------
__global__ __launch_bounds__(256) void vi_step(
    const float* __restrict__ vin, const float* __restrict__ qr,
    const float* __restrict__ ww, float* __restrict__ vout)
{
  const int tile = blockIdx.x;
  const int b    = tile >> 4;
  const int y0t  = (tile & 15) * 4;
  const int tid  = threadIdx.x;
  const int x    = tid & 63;
  const int ly   = tid >> 6;

  __shared__ float lv[8][68];
  for (int idx = tid; idx < 8 * 68; idx += 256) {
    int rr = idx / 68, c = idx - rr * 68;
    int yy = y0t + rr - 2, xx = c - 2;
    lv[rr][c] = (yy >= 0 && yy < 64 && xx >= 0 && xx < 64)
                    ? vin[((size_t)b << 12) + (yy << 6) + xx] : 0.f;
  }
  __syncthreads();

  float iv[5][5];
  #pragma unroll
  for (int ky = 0; ky < 5; ky++)
    #pragma unroll
    for (int kx = 0; kx < 5; kx++) iv[ky][kx] = lv[ly + ky][x + kx];

  const int y = y0t + ly;
  float vmax = -1e30f;
  #pragma unroll
  for (int a = 0; a < 10; a++) {
    float q = qr[((size_t)(b * 10 + a) << 12) + (y << 6) + x];
    #pragma unroll
    for (int ky = 0; ky < 5; ky++)
      #pragma unroll
      for (int kx = 0; kx < 5; kx++)
        q = fmaf(iv[ky][kx], ww[a * 25 + ky * 5 + kx], q);
    vmax = fmaxf(vmax, q);
  }
  vout[((size_t)b << 12) + (y << 6) + x] = vmax;
}

// ---------------- critic ---------------------------------------------------
__global__ __launch_bounds__(256) void critic_k(
    const float* __restrict__ v, const float* __restrict__ cvw,
    const float* __restrict__ cvb, float* __restrict__ out)
{
  const int b = blockIdx.x;
  const int tid = threadIdx.x;
  const float4* pv = (const float4*)(v + ((size_t)b << 12));
  const float4* pw = (const float4*)cvw;
  float s = 0.f;
  #pragma unroll
  for (int i = 0; i < 4; i++) {
    float4 a = pv[tid + 256 * i];
    float4 w = pw[tid + 256 * i];
    s += a.x * w.x + a.y * w.y + a.z * w.z + a.w * w.w;
  }
  s = wave_sum(s);
  __shared__ float ls[4];
  const int w = tid >> 6;
  if ((tid & 63) == 0) ls[w] = s;
  __syncthreads();
  if (tid == 0) out[b] = ls[0] + ls[1] + ls[2] + ls[3] + cvb[0];
}

// ---------------- action MLP ----------------------------------------------
__global__ __launch_bounds__(128) void action_k(
    const float* __restrict__ obs, const float* __restrict__ fc1w,
    const float* __restrict__ fc1b, const float* __restrict__ fc2w,
    const float* __restrict__ fc2b, float* __restrict__ out)
{
  const int b = blockIdx.x;
  const int j = threadIdx.x;
  __shared__ float ob[24];
  __shared__ float h[100];
  if (j < 24) ob[j] = obs[b * 24 + j];
  __syncthreads();
  if (j < 100) {
    float s = fc1b[j];
    #pragma unroll
    for (int k = 0; k < 24; k++) s = fmaf(ob[k], fc1w[j * 24 + k], s);
    h[j] = fmaxf(s, 0.f);
  }
  __syncthreads();
  if (j < 10) {
    float s = fc2b[j];
    for (int k = 0; k < 100; k++) s = fmaf(h[k], fc2w[j * 100 + k], s);
    out[128 + b * 10 + j] = fmaxf(s, 0.f);
  }
}

// ---------------------------------------------------------------------------
extern "C" void kernel_launch(void* const* d_in, const int* in_sizes, int n_in,
                              void* d_out, int out_size, void* d_ws,
                              size_t ws_size, hipStream_t stream)
{
  const float* X     = (const float*)d_in[0];
  const float* obs   = (const float*)d_in[1];
  const float* h1_w  = (const float*)d_in[2];
  const float* h1_b  = (const float*)d_in[3];
  const float* g1    = (const float*)d_in[4];
  const float* b1    = (const float*)d_in[5];
  const float* h2_w  = (const float*)d_in[6];
  const float* h2_b  = (const float*)d_in[7];
  const float* g2    = (const float*)d_in[8];
  const float* b2    = (const float*)d_in[9];
  const float* h3_w  = (const float*)d_in[10];
  const float* h3_b  = (const float*)d_in[11];
  const float* g3    = (const float*)d_in[12];
  const float* b3    = (const float*)d_in[13];
  const float* r_w   = (const float*)d_in[14];
  const float* q_w   = (const float*)d_in[15];
  const float* w_vi  = (const float*)d_in[16];
  const float* fc1_w = (const float*)d_in[17];
  const float* fc1_b = (const float*)d_in[18];
  const float* fc2_w = (const float*)d_in[19];
  const float* fc2_b = (const float*)d_in[20];
  const float* cv_w  = (const float*)d_in[21];
  const float* cv_b  = (const float*)d_in[22];
  // K (d_in[23]) fixed to 36 at setup; loop count is compile-time.

  char* ws = (char*)d_ws;
  // bf16 tensors
  unsigned short* t2 = (unsigned short*)ws;                      // 125,829,120 B
  unsigned short* t3 = (unsigned short*)(ws + 125829120ull);     // 104,857,600 B
  // stats block after t3 (alive across whole run)
  float* ST = (float*)(ws + 230686720ull);                       // 1480 floats
  float* S1 = ST +    0; float* Q1 = ST +  150; float* A1 = ST +  300; float* B1 = ST +  450;
  float* S2 = ST +  600; float* Q2 = ST +  720; float* A2 = ST +  840; float* B2 = ST +  960;
  float* S3 = ST + 1080; float* Q3 = ST + 1180; float* A3 = ST + 1280; float* B3 = ST + 1380;
  // VI-phase fp32 buffers aliased over t2 (t2 dead once conv3 completes)
  float* r  = (float*)ws;          // 524,288 f
  float* qr = r + 524288;          // 5,242,880 f
  float* vA = qr + 5242880;        // 524,288 f
  float* vB = vA + 524288;         // 524,288 f

  hipMemsetAsync(ST, 0, 1480 * sizeof(float), stream);

  // layer 1 stats (no store), finalize
  conv1_stats<<<dim3(128 * 8, 10), 256, 0, stream>>>(X, h1_w, h1_b, S1, Q1);
  bn_finalize<150><<<1, 256, 0, stream>>>(S1, Q1, g1, b1, A1, B1);

  // fused conv2 (recomputes h1 on the fly), then BN2 stats
  conv2_fused<<<128 * 16, 1024, 0, stream>>>(X, h1_w, h1_b, A1, B1, h2_w, h2_b, t2);
  bn_stats_bf16<120><<<dim3(120, 32), 256, 0, stream>>>(t2, S2, Q2);
  bn_finalize<120><<<1, 256, 0, stream>>>(S2, Q2, g2, b2, A2, B2);

  // fused conv3 (BN2+ReLU in staging), then BN3 stats
  conv3_fused<<<128 * 16, 1024, 0, stream>>>(t2, A2, B2, h3_w, h3_b, t3);
  bn_stats_bf16<100><<<dim3(100, 32), 256, 0, stream>>>(t3, S3, Q3);
  bn_finalize<100><<<1, 256, 0, stream>>>(S3, Q3, g3, b3, A3, B3);

  // BN3+ReLU+reward reduce -> r (overwrites dead t2 region)
  bn3_reduce_r<<<512, 256, 0, stream>>>(t3, A3, B3, r_w, r);

  // VI
  qr_init<<<128 * 16, 256, 0, stream>>>(r, q_w, qr, vA);
  for (int i = 0; i < 36; i++) {
    const float* vin = (i & 1) ? vB : vA;
    float* vout      = (i & 1) ? vA : vB;
    vi_step<<<128 * 16, 256, 0, stream>>>(vin, qr, w_vi, vout);
  }

  float* out = (float*)d_out;
  critic_k<<<128, 256, 0, stream>>>(vA, cv_w, cv_b, out);
  action_k<<<128, 128, 0, stream>>>(obs, fc1_w, fc1_b, fc2_w, fc2_b, out);
}

// Round 5
// 10840.883 us; speedup vs baseline: 1.0329x; 1.0329x over previous
//
#include <hip/hip_runtime.h>

// ---------------------------------------------------------------------------
// VIN on MI355X. R5 = bisection: R2-proven VALU conv kernels (math verbatim),
// NHWC bf16 t2/t3 plumbing + R4's NHWC stats/reduce kernels kept under test.
// t2 [524288][120] bf16, t3 [524288][104] bf16, VI fp32 aliased over dead t2.
// Peak ws ~224 MiB.
// ---------------------------------------------------------------------------

#define NHW 524288.0f

static __device__ __forceinline__ float bf2f(unsigned short u) {
  return __uint_as_float(((unsigned int)u) << 16);
}
static __device__ __forceinline__ unsigned short f2bf(float f) {
  unsigned int x = __float_as_uint(f);
  return (unsigned short)((x + 0x7fffu + ((x >> 16) & 1u)) >> 16);  // RNE
}
static __device__ __forceinline__ float wave_sum(float s) {
  #pragma unroll
  for (int off = 32; off > 0; off >>= 1) s += __shfl_down(s, off, 64);
  return s;
}

// ---------------- conv1 (2->150) stats-only (R2 verbatim) ------------------
__global__ __launch_bounds__(256) void conv1_stats(
    const float* __restrict__ X, const float* __restrict__ w1,
    const float* __restrict__ b1, float* __restrict__ S, float* __restrict__ Q)
{
  const int tile = blockIdx.x;             // 128*8
  const int b    = tile >> 3;
  const int y0t  = (tile & 7) * 8;
  const int co0  = blockIdx.y * 15;        // 10 groups of 15
  const int tid  = threadIdx.x;
  const int x    = tid & 63;
  const int ly0  = (tid >> 6) * 2;

  __shared__ float lin[2][10][66];
  for (int idx = tid; idx < 2 * 10 * 66; idx += 256) {
    int cc = idx / 660, rem = idx - cc * 660;
    int rr = rem / 66,  c   = rem - rr * 66;
    int yy = y0t + rr - 1, xx = c - 1;
    lin[cc][rr][c] = (yy >= 0 && yy < 64 && xx >= 0 && xx < 64)
                         ? X[((size_t)(b * 2 + cc) << 12) + (yy << 6) + xx] : 0.f;
  }
  __syncthreads();

  float iv[2][4][3];
  #pragma unroll
  for (int cc = 0; cc < 2; cc++)
    #pragma unroll
    for (int r = 0; r < 4; r++)
      #pragma unroll
      for (int c = 0; c < 3; c++) iv[cc][r][c] = lin[cc][ly0 + r][x + c];

  #pragma unroll
  for (int co = 0; co < 15; co++) {
    const float* w9 = w1 + (size_t)(co0 + co) * 18;
    float a0 = 0.f, a1 = 0.f;
    #pragma unroll
    for (int cc = 0; cc < 2; cc++)
      #pragma unroll
      for (int ky = 0; ky < 3; ky++)
        #pragma unroll
        for (int kx = 0; kx < 3; kx++) {
          float wv = w9[cc * 9 + ky * 3 + kx];
          a0 = fmaf(iv[cc][ky][kx],     wv, a0);
          a1 = fmaf(iv[cc][ky + 1][kx], wv, a1);
        }
    float bz = b1[co0 + co];
    float t0 = a0 + bz, t1 = a1 + bz;
    float s  = wave_sum(t0 + t1);
    float q  = wave_sum(t0 * t0 + t1 * t1);
    if ((tid & 63) == 0) {
      atomicAdd(&S[co0 + co], s);
      atomicAdd(&Q[co0 + co], q);
    }
  }
}

// ---------------- BN finalize ----------------------------------------------
template <int C>
__global__ void bn_finalize(const float* __restrict__ S, const float* __restrict__ Q,
                            const float* __restrict__ g, const float* __restrict__ be,
                            float* __restrict__ A, float* __restrict__ Bs)
{
  int c = threadIdx.x;
  if (c < C) {
    const float invN = 1.f / NHW;
    float m   = S[c] * invN;
    float var = fmaxf(Q[c] * invN - m * m, 0.f);
    float sc  = g[c] * rsqrtf(var + 1e-5f);
    A[c]  = sc;
    Bs[c] = be[c] - m * sc;
  }
}

// ---------------- fused conv2 (R2 math verbatim) -> t2 NHWC ----------------
__global__ __launch_bounds__(1024, 4) void conv2_fused(
    const float* __restrict__ X,  const float* __restrict__ w1,
    const float* __restrict__ b1, const float* __restrict__ A1,
    const float* __restrict__ B1, const float* __restrict__ w2,
    const float* __restrict__ b2, unsigned short* __restrict__ t2)
{
  const int tile = blockIdx.x;           // 128*16
  const int b    = tile >> 4;
  const int y0t  = (tile & 15) * 4;
  const int tid  = threadIdx.x;

  __shared__ float Xs[2][8][68];               // X rows y0t-2..y0t+5, cols -2..65
  __shared__ float w1s[2700];
  __shared__ float A1s[150], B1s[150], b1s[150];
  __shared__ unsigned short h1t[150 * 396];    // [ci][6 rows][66 cols] bf16

  for (int i = tid; i < 2700; i += 1024) w1s[i] = w1[i];
  for (int i = tid; i < 150; i += 1024) { A1s[i] = A1[i]; B1s[i] = B1[i]; b1s[i] = b1[i]; }
  for (int i = tid; i < 2 * 8 * 68; i += 1024) {
    int cc = i / 544, rem = i - cc * 544;
    int rr = rem / 68, c = rem - rr * 68;
    int yy = y0t - 2 + rr, xx = c - 2;
    Xs[cc][rr][c] = (yy >= 0 && yy < 64 && xx >= 0 && xx < 64)
                        ? X[((size_t)(b * 2 + cc) << 12) + (yy << 6) + xx] : 0.f;
  }
  __syncthreads();

  // h1 tile: rows y0t-1..y0t+4 (rr 0..5), cols -1..64 (cc 0..65)
  for (int i = tid; i < 150 * 396; i += 1024) {
    int ci = i / 396, rem = i - ci * 396;
    int rr = rem / 66, cc = rem - rr * 66;
    int gy = y0t - 1 + rr, gx = cc - 1;
    float v = 0.f;
    if (gy >= 0 && gy < 64 && gx >= 0 && gx < 64) {
      float acc = b1s[ci];
      #pragma unroll
      for (int c2 = 0; c2 < 2; c2++)
        #pragma unroll
        for (int ky = 0; ky < 3; ky++)
          #pragma unroll
          for (int kx = 0; kx < 3; kx++)
            acc = fmaf(Xs[c2][rr + ky][cc + kx], w1s[(ci * 2 + c2) * 9 + ky * 3 + kx], acc);
      v = fmaxf(fmaf(acc, A1s[ci], B1s[ci]), 0.f);
    }
    h1t[i] = f2bf(v);
  }
  __syncthreads();

  const int g  = __builtin_amdgcn_readfirstlane(tid >> 8);   // 0..3 -> 30 co each
  const int x  = tid & 63;
  const int ly = (tid >> 6) & 3;

  float acc[30];
  #pragma unroll
  for (int i = 0; i < 30; i++) acc[i] = 0.f;

  for (int ci = 0; ci < 150; ci++) {
    float iv[3][3];
    const unsigned short* hp = &h1t[ci * 396 + ly * 66 + x];
    #pragma unroll
    for (int ky = 0; ky < 3; ky++)
      #pragma unroll
      for (int kx = 0; kx < 3; kx++) iv[ky][kx] = bf2f(hp[ky * 66 + kx]);

    const float* wp = w2 + (size_t)g * 40500 + (size_t)ci * 9;
    #pragma unroll
    for (int co = 0; co < 30; co++) {
      const float* w9 = wp + (size_t)co * 1350;
      #pragma unroll
      for (int ky = 0; ky < 3; ky++)
        #pragma unroll
        for (int kx = 0; kx < 3; kx++)
          acc[co] = fmaf(iv[ky][kx], w9[ky * 3 + kx], acc[co]);
    }
  }

  // ---- NHWC store via LDS transpose (h1t dead -> reuse as outs[256][120]) --
  __syncthreads();                       // all reads of h1t complete
  unsigned short* outs = h1t;
  const int p_loc = ly * 64 + x;
  #pragma unroll
  for (int co = 0; co < 30; co++) {
    int coi = g * 30 + co;
    outs[p_loc * 120 + coi] = f2bf(acc[co] + b2[coi]);
  }
  __syncthreads();

  for (int i = tid; i < 256 * 15; i += 1024) {
    int p = i / 15, gq = i - p * 15;
    size_t gpx = ((size_t)b << 12) + ((y0t + (p >> 6)) << 6) + (p & 63);
    *(uint4*)(t2 + gpx * 120 + gq * 8) = *(const uint4*)(&outs[p * 120 + gq * 8]);
  }
}

// ---------------- fused conv3 (R2 math verbatim) NHWC in/out ---------------
__global__ __launch_bounds__(1024, 4) void conv3_fused(
    const unsigned short* __restrict__ t2, const float* __restrict__ A2,
    const float* __restrict__ B2, const float* __restrict__ w3,
    const float* __restrict__ b3, unsigned short* __restrict__ t3)
{
  const int tile = blockIdx.x;
  const int b    = tile >> 4;
  const int y0t  = (tile & 15) * 4;
  const int tid  = threadIdx.x;

  __shared__ unsigned short h2t[120 * 396];    // bf16 [ci][6][66]
  __shared__ float A2s[120], B2s[120];

  if (tid < 120) { A2s[tid] = A2[tid]; B2s[tid] = B2[tid]; }
  __syncthreads();

  // NHWC coalesced load + BN2 + ReLU, transposed into h2t[ci][rr][cc]
  for (int i = tid; i < 396 * 15; i += 1024) {
    int p = i / 15, gq = i - p * 15;           // p: halo px (rr*66+cc)
    int rr = p / 66, cc = p - rr * 66;
    int gy = y0t - 1 + rr, gx = cc - 1;
    if (gy >= 0 && gy < 64 && gx >= 0 && gx < 64) {
      size_t gpx = ((size_t)b << 12) + (gy << 6) + gx;
      union { uint4 v; unsigned short u[8]; } in;
      in.v = *(const uint4*)(t2 + gpx * 120 + gq * 8);
      #pragma unroll
      for (int j = 0; j < 8; j++) {
        int ci = gq * 8 + j;
        h2t[ci * 396 + p] = f2bf(fmaxf(fmaf(bf2f(in.u[j]), A2s[ci], B2s[ci]), 0.f));
      }
    } else {
      #pragma unroll
      for (int j = 0; j < 8; j++) h2t[(gq * 8 + j) * 396 + p] = 0;
    }
  }
  __syncthreads();

  const int g  = __builtin_amdgcn_readfirstlane(tid >> 8);   // 0..3 -> 25 co each
  const int x  = tid & 63;
  const int ly = (tid >> 6) & 3;

  float acc[25];
  #pragma unroll
  for (int i = 0; i < 25; i++) acc[i] = 0.f;

  for (int ci = 0; ci < 120; ci++) {
    float iv[3][3];
    const unsigned short* hp = &h2t[ci * 396 + ly * 66 + x];
    #pragma unroll
    for (int ky = 0; ky < 3; ky++)
      #pragma unroll
      for (int kx = 0; kx < 3; kx++) iv[ky][kx] = bf2f(hp[ky * 66 + kx]);

    const float* wp = w3 + (size_t)(g * 25) * 1080 + (size_t)ci * 9;
    #pragma unroll
    for (int co = 0; co < 25; co++) {
      const float* w9 = wp + (size_t)co * 1080;
      #pragma unroll
      for (int ky = 0; ky < 3; ky++)
        #pragma unroll
        for (int kx = 0; kx < 3; kx++)
          acc[co] = fmaf(iv[ky][kx], w9[ky * 3 + kx], acc[co]);
    }
  }

  // ---- NHWC store via LDS transpose (h2t dead -> outs[256][104]) ----------
  __syncthreads();
  unsigned short* outs = h2t;
  const int p_loc = ly * 64 + x;
  #pragma unroll
  for (int co = 0; co < 25; co++) {
    int coi = g * 25 + co;
    outs[p_loc * 104 + coi] = f2bf(acc[co] + b3[coi]);
  }
  if (g == 3) {
    outs[p_loc * 104 + 100] = 0; outs[p_loc * 104 + 101] = 0;
    outs[p_loc * 104 + 102] = 0; outs[p_loc * 104 + 103] = 0;
  }
  __syncthreads();

  for (int i = tid; i < 256 * 13; i += 1024) {
    int p = i / 13, gq = i - p * 13;
    size_t gpx = ((size_t)b << 12) + ((y0t + (p >> 6)) << 6) + (p & 63);
    *(uint4*)(t3 + gpx * 104 + gq * 8) = *(const uint4*)(&outs[p * 104 + gq * 8]);
  }
}

// ---------------- per-channel sums over NHWC bf16 tensor (R4, under test) --
template <int ST, int NG, int C>
__global__ __launch_bounds__(256) void nhwc_stats(
    const unsigned short* __restrict__ t, float* __restrict__ S, float* __restrict__ Q)
{
  const int tid = threadIdx.x;
  const int g   = tid & 15;
  const int pl  = tid >> 4;
  const bool valid = (g < NG);
  const int px0 = blockIdx.x * 512;

  __shared__ float ss[128], qq[128];
  for (int i = tid; i < 128; i += 256) { ss[i] = 0.f; qq[i] = 0.f; }
  __syncthreads();

  float s8[8], q8[8];
  #pragma unroll
  for (int j = 0; j < 8; j++) { s8[j] = 0.f; q8[j] = 0.f; }

  if (valid) {
    for (int it = 0; it < 32; it++) {
      size_t px = px0 + it * 16 + pl;
      union { uint4 v; unsigned short u[8]; } in;
      in.v = *(const uint4*)(t + px * ST + g * 8);
      #pragma unroll
      for (int j = 0; j < 8; j++) {
        float v = bf2f(in.u[j]);
        s8[j] += v;
        q8[j] += v * v;
      }
    }
    #pragma unroll
    for (int j = 0; j < 8; j++) {
      atomicAdd(&ss[g * 8 + j], s8[j]);
      atomicAdd(&qq[g * 8 + j], q8[j]);
    }
  }
  __syncthreads();
  if (tid < C) {
    atomicAdd(&S[tid], ss[tid]);
    atomicAdd(&Q[tid], qq[tid]);
  }
}

// ---------------- BN3+ReLU+1x1 reward reduce (R4, under test) --------------
__global__ __launch_bounds__(256) void bn3_reduce_r(
    const unsigned short* __restrict__ t3, const float* __restrict__ A3,
    const float* __restrict__ B3, const float* __restrict__ rw,
    float* __restrict__ r)
{
  __shared__ float A3s[104], B3s[104], rws[104];
  const int tid = threadIdx.x;
  for (int i = tid; i < 104; i += 256) {
    bool v = (i < 100);
    A3s[i] = v ? A3[i] : 0.f;
    B3s[i] = v ? B3[i] : 0.f;
    rws[i] = v ? rw[i] : 0.f;
  }
  __syncthreads();

  size_t px = (size_t)blockIdx.x * 256 + tid;
  const unsigned short* p = t3 + px * 104;
  float a = 0.f;
  #pragma unroll
  for (int gq = 0; gq < 13; gq++) {
    union { uint4 v; unsigned short u[8]; } in;
    in.v = *(const uint4*)(p + gq * 8);
    #pragma unroll
    for (int j = 0; j < 8; j++) {
      int ci = gq * 8 + j;
      a = fmaf(fmaxf(fmaf(bf2f(in.u[j]), A3s[ci], B3s[ci]), 0.f), rws[ci], a);
    }
  }
  r[px] = a;
}

// ---------------- qr = conv5x5(r, q_w); v0 = max_a qr ----------------------
__global__ __launch_bounds__(256) void qr_init(
    const float* __restrict__ r, const float* __restrict__ qw,
    float* __restrict__ qr, float* __restrict__ v0)
{
  const int tile = blockIdx.x;          // 128*16
  const int b    = tile >> 4;
  const int y0t  = (tile & 15) * 4;
  const int tid  = threadIdx.x;
  const int x    = tid & 63;
  const int ly   = tid >> 6;

  __shared__ float lv[8][68];
  for (int idx = tid; idx < 8 * 68; idx += 256) {
    int rr = idx / 68, c = idx - rr * 68;
    int yy = y0t + rr - 2, xx = c - 2;
    lv[rr][c] = (yy >= 0 && yy < 64 && xx >= 0 && xx < 64)
                    ? r[((size_t)b << 12) + (yy << 6) + xx] : 0.f;
  }
  __syncthreads();

  float iv[5][5];
  #pragma unroll
  for (int ky = 0; ky < 5; ky++)
    #pragma unroll
    for (int kx = 0; kx < 5; kx++) iv[ky][kx] = lv[ly + ky][x + kx];

  const int y = y0t + ly;
  float vmax = -1e30f;
  #pragma unroll
  for (int a = 0; a < 10; a++) {
    float q = 0.f;
    #pragma unroll
    for (int ky = 0; ky < 5; ky++)
      #pragma unroll
      for (int kx = 0; kx < 5; kx++)
        q = fmaf(iv[ky][kx], qw[a * 25 + ky * 5 + kx], q);
    qr[((size_t)(b * 10 + a) << 12) + (y << 6) + x] = q;
    vmax = fmaxf(vmax, q);
  }
  v0[((size_t)b << 12) + (y << 6) + x] = vmax;
}

// ---------------- VI step: v' = max_a (qr + conv5x5(v, w)) -----------------
__global__ __launch_bounds__(256) void vi_step(
    const float* __restrict__ vin, const float* __restrict__ qr,
    const float* __restrict__ ww, float* __restrict__ vout)
{
  const int tile = blockIdx.x;
  const int b    = tile >> 4;
  const int y0t  = (tile & 15) * 4;
  const int tid  = threadIdx.x;
  const int x    = tid & 63;
  const int ly   = tid >> 6;

  __shared__ float lv[8][68];
  for (int idx = tid; idx < 8 * 68; idx += 256) {
    int rr = idx / 68, c = idx - rr * 68;
    int yy = y0t + rr - 2, xx = c - 2;
    lv[rr][c] = (yy >= 0 && yy < 64 && xx >= 0 && xx < 64)
                    ? vin[((size_t)b << 12) + (yy << 6) + xx] : 0.f;
  }
  __syncthreads();

  float iv[5][5];
  #pragma unroll
  for (int ky = 0; ky < 5; ky++)
    #pragma unroll
    for (int kx = 0; kx < 5; kx++) iv[ky][kx] = lv[ly + ky][x + kx];

  const int y = y0t + ly;
  float vmax = -1e30f;
  #pragma unroll
  for (int a = 0; a < 10; a++) {
    float q = qr[((size_t)(b * 10 + a) << 12) + (y << 6) + x];
    #pragma unroll
    for (int ky = 0; ky < 5; ky++)
      #pragma unroll
      for (int kx = 0; kx < 5; kx++)
        q = fmaf(iv[ky][kx], ww[a * 25 + ky * 5 + kx], q);
    vmax = fmaxf(vmax, q);
  }
  vout[((size_t)b << 12) + (y << 6) + x] = vmax;
}

// ---------------- critic ---------------------------------------------------
__global__ __launch_bounds__(256) void critic_k(
    const float* __restrict__ v, const float* __restrict__ cvw,
    const float* __restrict__ cvb, float* __restrict__ out)
{
  const int b = blockIdx.x;
  const int tid = threadIdx.x;
  const float4* pv = (const float4*)(v + ((size_t)b << 12));
  const float4* pw = (const float4*)cvw;
  float s = 0.f;
  #pragma unroll
  for (int i = 0; i < 4; i++) {
    float4 a = pv[tid + 256 * i];
    float4 w = pw[tid + 256 * i];
    s += a.x * w.x + a.y * w.y + a.z * w.z + a.w * w.w;
  }
  s = wave_sum(s);
  __shared__ float ls[4];
  const int w = tid >> 6;
  if ((tid & 63) == 0) ls[w] = s;
  __syncthreads();
  if (tid == 0) out[b] = ls[0] + ls[1] + ls[2] + ls[3] + cvb[0];
}

// ---------------- action MLP ----------------------------------------------
__global__ __launch_bounds__(128) void action_k(
    const float* __restrict__ obs, const float* __restrict__ fc1w,
    const float* __restrict__ fc1b, const float* __restrict__ fc2w,
    const float* __restrict__ fc2b, float* __restrict__ out)
{
  const int b = blockIdx.x;
  const int j = threadIdx.x;
  __shared__ float ob[24];
  __shared__ float h[100];
  if (j < 24) ob[j] = obs[b * 24 + j];
  __syncthreads();
  if (j < 100) {
    float s = fc1b[j];
    #pragma unroll
    for (int k = 0; k < 24; k++) s = fmaf(ob[k], fc1w[j * 24 + k], s);
    h[j] = fmaxf(s, 0.f);
  }
  __syncthreads();
  if (j < 10) {
    float s = fc2b[j];
    for (int k = 0; k < 100; k++) s = fmaf(h[k], fc2w[j * 100 + k], s);
    out[128 + b * 10 + j] = fmaxf(s, 0.f);
  }
}

// ---------------------------------------------------------------------------
extern "C" void kernel_launch(void* const* d_in, const int* in_sizes, int n_in,
                              void* d_out, int out_size, void* d_ws,
                              size_t ws_size, hipStream_t stream)
{
  const float* X     = (const float*)d_in[0];
  const float* obs   = (const float*)d_in[1];
  const float* h1_w  = (const float*)d_in[2];
  const float* h1_b  = (const float*)d_in[3];
  const float* g1    = (const float*)d_in[4];
  const float* b1    = (const float*)d_in[5];
  const float* h2_w  = (const float*)d_in[6];
  const float* h2_b  = (const float*)d_in[7];
  const float* g2    = (const float*)d_in[8];
  const float* b2    = (const float*)d_in[9];
  const float* h3_w  = (const float*)d_in[10];
  const float* h3_b  = (const float*)d_in[11];
  const float* g3    = (const float*)d_in[12];
  const float* b3    = (const float*)d_in[13];
  const float* r_w   = (const float*)d_in[14];
  const float* q_w   = (const float*)d_in[15];
  const float* w_vi  = (const float*)d_in[16];
  const float* fc1_w = (const float*)d_in[17];
  const float* fc1_b = (const float*)d_in[18];
  const float* fc2_w = (const float*)d_in[19];
  const float* fc2_b = (const float*)d_in[20];
  const float* cv_w  = (const float*)d_in[21];
  const float* cv_b  = (const float*)d_in[22];
  // K (d_in[23]) fixed to 36 by setup; loop count is compile-time.

  char* ws = (char*)d_ws;
  unsigned short* t2 = (unsigned short*)ws;                      // 125,829,120 B
  unsigned short* t3 = (unsigned short*)(ws + 125829120ull);     // 109,051,904 B
  float*          ST = (float*)         (ws + 234881024ull);     //       5,920 B
  float* S1 = ST +    0; float* Q1 = ST +  150; float* A1 = ST +  300; float* B1 = ST +  450;
  float* S2 = ST +  600; float* Q2 = ST +  720; float* A2 = ST +  840; float* B2 = ST +  960;
  float* S3 = ST + 1080; float* Q3 = ST + 1180; float* A3 = ST + 1280; float* B3 = ST + 1380;
  // VI fp32 buffers aliased over dead t2 region
  float* r  = (float*)ws;          // 524,288 f
  float* qr = r + 524288;          // 5,242,880 f
  float* vA = qr + 5242880;        // 524,288 f
  float* vB = vA + 524288;         // 524,288 f

  hipMemsetAsync(ST, 0, 1480 * sizeof(float), stream);

  conv1_stats<<<dim3(1024, 10), 256, 0, stream>>>(X, h1_w, h1_b, S1, Q1);
  bn_finalize<150><<<1, 256, 0, stream>>>(S1, Q1, g1, b1, A1, B1);

  conv2_fused<<<2048, 1024, 0, stream>>>(X, h1_w, h1_b, A1, B1, h2_w, h2_b, t2);
  nhwc_stats<120, 15, 120><<<1024, 256, 0, stream>>>(t2, S2, Q2);
  bn_finalize<120><<<1, 256, 0, stream>>>(S2, Q2, g2, b2, A2, B2);

  conv3_fused<<<2048, 1024, 0, stream>>>(t2, A2, B2, h3_w, h3_b, t3);
  nhwc_stats<104, 13, 100><<<1024, 256, 0, stream>>>(t3, S3, Q3);
  bn_finalize<100><<<1, 256, 0, stream>>>(S3, Q3, g3, b3, A3, B3);

  bn3_reduce_r<<<2048, 256, 0, stream>>>(t3, A3, B3, r_w, r);

  qr_init<<<2048, 256, 0, stream>>>(r, q_w, qr, vA);
  for (int i = 0; i < 36; i++) {
    const float* vin = (i & 1) ? vB : vA;
    float* vout      = (i & 1) ? vA : vB;
    vi_step<<<2048, 256, 0, stream>>>(vin, qr, w_vi, vout);
  }

  float* out = (float*)d_out;
  critic_k<<<128, 256, 0, stream>>>(vA, cv_w, cv_b, out);
  action_k<<<128, 128, 0, stream>>>(obs, fc1_w, fc1_b, fc2_w, fc2_b, out);
}

// Round 6
// 2818.193 us; speedup vs baseline: 3.9731x; 3.8467x over previous
//
#include <hip/hip_runtime.h>

// ---------------------------------------------------------------------------
// VIN on MI355X (gfx950). B=128, H=W=64, C: 2 -> 150 -> 120 -> 100, q=10, K=36.
// R6: MFMA implicit-GEMM conv2/conv3 (16x16x32 bf16), split-bf16 weights
//     (hi+lo => fp32-accurate weights). FIX vs R3/R4: conv3 B-tile staging
//     copied 544 uint4 instead of 1088 (half the weight tile was garbage).
// NHWC bf16 t2 [524288][120], t3 [524288][104]; VI fp32 aliased over dead t2.
// ---------------------------------------------------------------------------

#define NHW 524288.0f

typedef __attribute__((ext_vector_type(8))) short v8s;
typedef __attribute__((ext_vector_type(4))) float v4f;

static __device__ __forceinline__ float bf2f(unsigned short u) {
  return __uint_as_float(((unsigned int)u) << 16);
}
static __device__ __forceinline__ unsigned short f2bf(float f) {
  unsigned int x = __float_as_uint(f);
  return (unsigned short)((x + 0x7fffu + ((x >> 16) & 1u)) >> 16);  // RNE
}
static __device__ __forceinline__ float wave_sum(float s) {
  #pragma unroll
  for (int off = 32; off > 0; off >>= 1) s += __shfl_down(s, off, 64);
  return s;
}

// -------- weight repack + hi/lo split: w[co][ci][3][3] -> [9][128][CIP] ----
template <int CO, int CI, int CIP>
__global__ __launch_bounds__(256) void repack_w(
    const float* __restrict__ w, unsigned short* __restrict__ Whi,
    unsigned short* __restrict__ Wlo)
{
  int i = blockIdx.x * 256 + threadIdx.x;
  const int total = 9 * 128 * CIP;
  if (i >= total) return;
  int pos = i / (128 * CIP);
  int rem = i - pos * (128 * CIP);
  int co  = rem / CIP;
  int ci  = rem - co * CIP;
  float v = (co < CO && ci < CI) ? w[(co * CI + ci) * 9 + pos] : 0.f;
  unsigned short hi = f2bf(v);
  Whi[i] = hi;
  Wlo[i] = f2bf(v - bf2f(hi));
}

// ---------------- conv1 (2->150) stats-only, LDS-accumulated ---------------
__global__ __launch_bounds__(256) void conv1_stats(
    const float* __restrict__ X, const float* __restrict__ w1,
    const float* __restrict__ b1, float* __restrict__ S, float* __restrict__ Q)
{
  const int tile = blockIdx.x;             // 128*8
  const int b    = tile >> 3;
  const int y0t  = (tile & 7) * 8;
  const int co0  = blockIdx.y * 15;        // 10 groups of 15
  const int tid  = threadIdx.x;
  const int x    = tid & 63;
  const int ly0  = (tid >> 6) * 2;

  __shared__ float lin[2][10][66];
  __shared__ float ss[15], qq[15];
  if (tid < 15) { ss[tid] = 0.f; qq[tid] = 0.f; }
  for (int idx = tid; idx < 2 * 10 * 66; idx += 256) {
    int cc = idx / 660, rem = idx - cc * 660;
    int rr = rem / 66,  c   = rem - rr * 66;
    int yy = y0t + rr - 1, xx = c - 1;
    lin[cc][rr][c] = (yy >= 0 && yy < 64 && xx >= 0 && xx < 64)
                         ? X[((size_t)(b * 2 + cc) << 12) + (yy << 6) + xx] : 0.f;
  }
  __syncthreads();

  float iv[2][4][3];
  #pragma unroll
  for (int cc = 0; cc < 2; cc++)
    #pragma unroll
    for (int r = 0; r < 4; r++)
      #pragma unroll
      for (int c = 0; c < 3; c++) iv[cc][r][c] = lin[cc][ly0 + r][x + c];

  #pragma unroll
  for (int co = 0; co < 15; co++) {
    const float* w9 = w1 + (size_t)(co0 + co) * 18;
    float a0 = 0.f, a1 = 0.f;
    #pragma unroll
    for (int cc = 0; cc < 2; cc++)
      #pragma unroll
      for (int ky = 0; ky < 3; ky++)
        #pragma unroll
        for (int kx = 0; kx < 3; kx++) {
          float wv = w9[cc * 9 + ky * 3 + kx];
          a0 = fmaf(iv[cc][ky][kx],     wv, a0);
          a1 = fmaf(iv[cc][ky + 1][kx], wv, a1);
        }
    float bz = b1[co0 + co];
    float t0 = a0 + bz, t1 = a1 + bz;
    float s  = wave_sum(t0 + t1);
    float q  = wave_sum(t0 * t0 + t1 * t1);
    if ((tid & 63) == 0) { atomicAdd(&ss[co], s); atomicAdd(&qq[co], q); }
  }
  __syncthreads();
  if (tid < 15) {
    atomicAdd(&S[co0 + tid], ss[tid]);
    atomicAdd(&Q[co0 + tid], qq[tid]);
  }
}

// ---------------- BN finalize ----------------------------------------------
template <int C>
__global__ void bn_finalize(const float* __restrict__ S, const float* __restrict__ Q,
                            const float* __restrict__ g, const float* __restrict__ be,
                            float* __restrict__ A, float* __restrict__ Bs)
{
  int c = threadIdx.x;
  if (c < C) {
    const float invN = 1.f / NHW;
    float m   = S[c] * invN;
    float var = fmaxf(Q[c] * invN - m * m, 0.f);
    float sc  = g[c] * rsqrtf(var + 1e-5f);
    A[c]  = sc;
    Bs[c] = be[c] - m * sc;
  }
}

// ---------------- conv2 MFMA (split-B): h1 recompute -> 64px x 64co --------
__global__ __launch_bounds__(256, 2) void conv2_mfma(
    const float* __restrict__ X,  const float* __restrict__ w1,
    const float* __restrict__ b1f, const float* __restrict__ A1,
    const float* __restrict__ B1, const unsigned short* __restrict__ W2h,
    const unsigned short* __restrict__ W2l,
    const float* __restrict__ b2, unsigned short* __restrict__ t2)
{
  const int bx   = blockIdx.x;
  const int b    = bx >> 6;
  const int tile = bx & 63;
  const int y0   = (tile >> 3) * 8;
  const int x0   = (tile & 7) * 8;
  const int cg   = blockIdx.y;           // 0/1 -> co base 0/64
  const int tid  = threadIdx.x;
  const int lane = tid & 63;
  const int wid  = __builtin_amdgcn_readfirstlane(tid >> 6);
  const int wm   = wid >> 1;
  const int wn   = wid & 1;
  const int quad = (lane >> 4) * 8;

  __shared__ __align__(16) float Xs[2][12][12];
  __shared__ __align__(16) unsigned short Atile[100 * 168];
  __shared__ __align__(16) unsigned short Btile[64 * 168];   // reused as outs[64][72]
  __shared__ float b2s[64];

  for (int i = tid; i < 288; i += 256) {
    int c2 = i / 144, rem = i - c2 * 144;
    int r = rem / 12, c = rem - r * 12;
    int gy = y0 - 2 + r, gx = x0 - 2 + c;
    Xs[c2][r][c] = (gy >= 0 && gy < 64 && gx >= 0 && gx < 64)
                       ? X[((size_t)(b * 2 + c2) << 12) + (gy << 6) + gx] : 0.f;
  }
  if (tid < 64) {
    int co = cg * 64 + tid;
    b2s[tid] = (co < 120) ? b2[co] : 0.f;
  }
  __syncthreads();

  // h1 tile (conv1+BN1+ReLU) -> Atile [100 px][168 ci] bf16
  for (int ci = wid; ci < 150; ci += 4) {
    float sc = A1[ci], sh = B1[ci], bz = b1f[ci];
    const float* w9 = w1 + (size_t)ci * 18;
    float wv[18];
    #pragma unroll
    for (int k = 0; k < 18; k++) wv[k] = w9[k];
    for (int p = lane; p < 100; p += 64) {
      int py = p / 10, px = p - py * 10;
      int hy = y0 - 1 + py, hx = x0 - 1 + px;
      float v = 0.f;
      if (hy >= 0 && hy < 64 && hx >= 0 && hx < 64) {
        float acc = bz;
        #pragma unroll
        for (int c2 = 0; c2 < 2; c2++)
          #pragma unroll
          for (int ky = 0; ky < 3; ky++)
            #pragma unroll
            for (int kx = 0; kx < 3; kx++)
              acc = fmaf(Xs[c2][py + ky][px + kx], wv[c2 * 9 + ky * 3 + kx], acc);
        v = fmaxf(fmaf(acc, sc, sh), 0.f);
      }
      Atile[p * 168 + ci] = f2bf(v);
    }
  }
  for (int i = tid; i < 1000; i += 256) {        // zero K-pad ci 150..159
    int p = i / 10;
    Atile[p * 168 + 150 + (i - p * 10)] = 0;
  }

  v4f acc[2][2];
  #pragma unroll
  for (int i = 0; i < 2; i++)
    #pragma unroll
    for (int j = 0; j < 2; j++) acc[i][j] = (v4f){0.f, 0.f, 0.f, 0.f};

  const int m0 = wm * 32 + (lane & 15);
  const int n0 = wn * 32 + (lane & 15);

  for (int pos = 0; pos < 9; pos++) {
    const int ky = pos / 3, kx = pos - ky * 3;
    const int ra0 = (((m0 >> 3) + ky) * 10 + (m0 & 7) + kx) * 168;
    const int m1  = m0 + 16;
    const int ra1 = (((m1 >> 3) + ky) * 10 + (m1 & 7) + kx) * 168;
    const int rb0 = n0 * 168;
    const int rb1 = (n0 + 16) * 168;

    for (int half = 0; half < 2; half++) {
      __syncthreads();   // prior reads of Btile done (first iter: Atile ready)
      const unsigned short* src =
          (half ? W2l : W2h) + ((size_t)pos * 128 + cg * 64) * 168;
      for (int i = tid; i < 1344; i += 256)       // 64*168/8 = 1344 uint4
        ((uint4*)Btile)[i] = ((const uint4*)src)[i];
      __syncthreads();

      #pragma unroll
      for (int kc = 0; kc < 5; kc++) {
        const int ko = kc * 32 + quad;
        v8s a0 = *(const v8s*)(&Atile[ra0 + ko]);
        v8s a1 = *(const v8s*)(&Atile[ra1 + ko]);
        v8s bb0 = *(const v8s*)(&Btile[rb0 + ko]);
        v8s bb1 = *(const v8s*)(&Btile[rb1 + ko]);
        acc[0][0] = __builtin_amdgcn_mfma_f32_16x16x32_bf16(a0, bb0, acc[0][0], 0, 0, 0);
        acc[0][1] = __builtin_amdgcn_mfma_f32_16x16x32_bf16(a0, bb1, acc[0][1], 0, 0, 0);
        acc[1][0] = __builtin_amdgcn_mfma_f32_16x16x32_bf16(a1, bb0, acc[1][0], 0, 0, 0);
        acc[1][1] = __builtin_amdgcn_mfma_f32_16x16x32_bf16(a1, bb1, acc[1][1], 0, 0, 0);
      }
    }
  }
  __syncthreads();

  unsigned short* outs = Btile;
  #pragma unroll
  for (int mi = 0; mi < 2; mi++)
    #pragma unroll
    for (int nj = 0; nj < 2; nj++) {
      int n = wn * 32 + nj * 16 + (lane & 15);
      float bz = b2s[n];
      #pragma unroll
      for (int r = 0; r < 4; r++) {
        int m = wm * 32 + mi * 16 + (lane >> 4) * 4 + r;
        outs[m * 72 + n] = f2bf(acc[mi][nj][r] + bz);
      }
    }
  __syncthreads();

  const int ngroups = cg ? 7 : 8;
  for (int i = tid; i < 64 * ngroups; i += 256) {
    int p = i / ngroups, g = i - p * ngroups;
    int gy = y0 + (p >> 3), gx = x0 + (p & 7);
    size_t gpx = ((size_t)b << 12) + (gy << 6) + gx;
    *(uint4*)(t2 + gpx * 120 + cg * 64 + g * 8) = *(const uint4*)(&outs[p * 72 + g * 8]);
  }
}

// ---------------- conv3 MFMA (split-B): BN2+ReLU(t2) -> 64px x 64co --------
__global__ __launch_bounds__(256, 2) void conv3_mfma(
    const unsigned short* __restrict__ t2, const float* __restrict__ A2,
    const float* __restrict__ B2, const unsigned short* __restrict__ W3h,
    const unsigned short* __restrict__ W3l,
    const float* __restrict__ b3, unsigned short* __restrict__ t3)
{
  const int bx   = blockIdx.x;
  const int b    = bx >> 6;
  const int tile = bx & 63;
  const int y0   = (tile >> 3) * 8;
  const int x0   = (tile & 7) * 8;
  const int cg   = blockIdx.y;
  const int tid  = threadIdx.x;
  const int lane = tid & 63;
  const int wid  = __builtin_amdgcn_readfirstlane(tid >> 6);
  const int wm   = wid >> 1;
  const int wn   = wid & 1;
  const int quad = (lane >> 4) * 8;

  __shared__ __align__(16) unsigned short Atile[100 * 136];
  __shared__ __align__(16) unsigned short Btile[2][64 * 136]; // hi, lo; reused as outs
  __shared__ float A2s[120], B2s[120];
  __shared__ float b3s[64];

  if (tid < 120) { A2s[tid] = A2[tid]; B2s[tid] = B2[tid]; }
  if (tid < 64) {
    int co = cg * 64 + tid;
    b3s[tid] = (co < 100) ? b3[co] : 0.f;
  }
  __syncthreads();

  for (int i = tid; i < 1500; i += 256) {          // 100 px x 15 ushort8
    int p = i / 15, g = i - p * 15;
    int py = p / 10, px = p - py * 10;
    int gy = y0 - 1 + py, gx = x0 - 1 + px;
    union { uint4 v; unsigned short u[8]; } in, out;
    if (gy >= 0 && gy < 64 && gx >= 0 && gx < 64) {
      size_t gpx = ((size_t)b << 12) + (gy << 6) + gx;
      in.v = *(const uint4*)(t2 + gpx * 120 + g * 8);
      #pragma unroll
      for (int j = 0; j < 8; j++) {
        int ci = g * 8 + j;
        out.u[j] = f2bf(fmaxf(fmaf(bf2f(in.u[j]), A2s[ci], B2s[ci]), 0.f));
      }
    } else {
      out.v = (uint4){0, 0, 0, 0};
    }
    *(uint4*)(&Atile[p * 136 + g * 8]) = out.v;
  }
  for (int i = tid; i < 800; i += 256) {           // zero K-pad ci 120..127
    int p = i >> 3;
    Atile[p * 136 + 120 + (i & 7)] = 0;
  }

  v4f acc[2][2];
  #pragma unroll
  for (int i = 0; i < 2; i++)
    #pragma unroll
    for (int j = 0; j < 2; j++) acc[i][j] = (v4f){0.f, 0.f, 0.f, 0.f};

  const int m0 = wm * 32 + (lane & 15);
  const int n0 = wn * 32 + (lane & 15);

  for (int pos = 0; pos < 9; pos++) {
    __syncthreads();   // prior reads of Btile done (first iter: Atile ready)
    {
      const unsigned short* sh_ = W3h + ((size_t)pos * 128 + cg * 64) * 136;
      const unsigned short* sl_ = W3l + ((size_t)pos * 128 + cg * 64) * 136;
      for (int i = tid; i < 1088; i += 256) {      // FIX: 64*136/8 = 1088 uint4
        ((uint4*)Btile[0])[i] = ((const uint4*)sh_)[i];
        ((uint4*)Btile[1])[i] = ((const uint4*)sl_)[i];
      }
    }
    __syncthreads();

    const int ky = pos / 3, kx = pos - ky * 3;
    const int ra0 = (((m0 >> 3) + ky) * 10 + (m0 & 7) + kx) * 136;
    const int m1  = m0 + 16;
    const int ra1 = (((m1 >> 3) + ky) * 10 + (m1 & 7) + kx) * 136;
    const int rb0 = n0 * 136;
    const int rb1 = (n0 + 16) * 136;

    #pragma unroll
    for (int half = 0; half < 2; half++) {
      #pragma unroll
      for (int kc = 0; kc < 4; kc++) {
        const int ko = kc * 32 + quad;
        v8s a0 = *(const v8s*)(&Atile[ra0 + ko]);
        v8s a1 = *(const v8s*)(&Atile[ra1 + ko]);
        v8s bb0 = *(const v8s*)(&Btile[half][rb0 + ko]);
        v8s bb1 = *(const v8s*)(&Btile[half][rb1 + ko]);
        acc[0][0] = __builtin_amdgcn_mfma_f32_16x16x32_bf16(a0, bb0, acc[0][0], 0, 0, 0);
        acc[0][1] = __builtin_amdgcn_mfma_f32_16x16x32_bf16(a0, bb1, acc[0][1], 0, 0, 0);
        acc[1][0] = __builtin_amdgcn_mfma_f32_16x16x32_bf16(a1, bb0, acc[1][0], 0, 0, 0);
        acc[1][1] = __builtin_amdgcn_mfma_f32_16x16x32_bf16(a1, bb1, acc[1][1], 0, 0, 0);
      }
    }
  }
  __syncthreads();

  unsigned short* outs = Btile[0];
  #pragma unroll
  for (int mi = 0; mi < 2; mi++)
    #pragma unroll
    for (int nj = 0; nj < 2; nj++) {
      int n = wn * 32 + nj * 16 + (lane & 15);
      float bz = b3s[n];
      #pragma unroll
      for (int r = 0; r < 4; r++) {
        int m = wm * 32 + mi * 16 + (lane >> 4) * 4 + r;
        outs[m * 72 + n] = f2bf(acc[mi][nj][r] + bz);
      }
    }
  __syncthreads();

  const int ngroups = cg ? 5 : 8;     // cg=1: co 64..103 (100..103 store zeros)
  for (int i = tid; i < 64 * ngroups; i += 256) {
    int p = i / ngroups, g = i - p * ngroups;
    int gy = y0 + (p >> 3), gx = x0 + (p & 7);
    size_t gpx = ((size_t)b << 12) + (gy << 6) + gx;
    *(uint4*)(t3 + gpx * 104 + cg * 64 + g * 8) = *(const uint4*)(&outs[p * 72 + g * 8]);
  }
}

// ---------------- per-channel sums over NHWC bf16 tensor -------------------
template <int ST, int NG, int C>
__global__ __launch_bounds__(256) void nhwc_stats(
    const unsigned short* __restrict__ t, float* __restrict__ S, float* __restrict__ Q)
{
  const int tid = threadIdx.x;
  const int g   = tid & 15;
  const int pl  = tid >> 4;
  const bool valid = (g < NG);
  const int px0 = blockIdx.x * 512;

  __shared__ float ss[128], qq[128];
  for (int i = tid; i < 128; i += 256) { ss[i] = 0.f; qq[i] = 0.f; }
  __syncthreads();

  float s8[8], q8[8];
  #pragma unroll
  for (int j = 0; j < 8; j++) { s8[j] = 0.f; q8[j] = 0.f; }

  if (valid) {
    for (int it = 0; it < 32; it++) {
      size_t px = px0 + it * 16 + pl;
      union { uint4 v; unsigned short u[8]; } in;
      in.v = *(const uint4*)(t + px * ST + g * 8);
      #pragma unroll
      for (int j = 0; j < 8; j++) {
        float v = bf2f(in.u[j]);
        s8[j] += v;
        q8[j] += v * v;
      }
    }
    #pragma unroll
    for (int j = 0; j < 8; j++) {
      atomicAdd(&ss[g * 8 + j], s8[j]);
      atomicAdd(&qq[g * 8 + j], q8[j]);
    }
  }
  __syncthreads();
  if (tid < C) {
    atomicAdd(&S[tid], ss[tid]);
    atomicAdd(&Q[tid], qq[tid]);
  }
}

// ---------------- BN3+ReLU+1x1 reward reduce over NHWC t3 ------------------
__global__ __launch_bounds__(256) void bn3_reduce_r(
    const unsigned short* __restrict__ t3, const float* __restrict__ A3,
    const float* __restrict__ B3, const float* __restrict__ rw,
    float* __restrict__ r)
{
  __shared__ float A3s[104], B3s[104], rws[104];
  const int tid = threadIdx.x;
  for (int i = tid; i < 104; i += 256) {
    bool v = (i < 100);
    A3s[i] = v ? A3[i] : 0.f;
    B3s[i] = v ? B3[i] : 0.f;
    rws[i] = v ? rw[i] : 0.f;
  }
  __syncthreads();

  size_t px = (size_t)blockIdx.x * 256 + tid;
  const unsigned short* p = t3 + px * 104;
  float a = 0.f;
  #pragma unroll
  for (int gq = 0; gq < 13; gq++) {
    union { uint4 v; unsigned short u[8]; } in;
    in.v = *(const uint4*)(p + gq * 8);
    #pragma unroll
    for (int j = 0; j < 8; j++) {
      int ci = gq * 8 + j;
      a = fmaf(fmaxf(fmaf(bf2f(in.u[j]), A3s[ci], B3s[ci]), 0.f), rws[ci], a);
    }
  }
  r[px] = a;
}

// ---------------- qr = conv5x5(r, q_w); v0 = max_a qr ----------------------
__global__ __launch_bounds__(256) void qr_init(
    const float* __restrict__ r, const float* __restrict__ qw,
    float* __restrict__ qr, float* __restrict__ v0)
{
  const int tile = blockIdx.x;          // 128*16
  const int b    = tile >> 4;
  const int y0t  = (tile & 15) * 4;
  const int tid  = threadIdx.x;
  const int x    = tid & 63;
  const int ly   = tid >> 6;

  __shared__ float lv[8][68];
  for (int idx = tid; idx < 8 * 68; idx += 256) {
    int rr = idx / 68, c = idx - rr * 68;
    int yy = y0t + rr - 2, xx = c - 2;
    lv[rr][c] = (yy >= 0 && yy < 64 && xx >= 0 && xx < 64)
                    ? r[((size_t)b << 12) + (yy << 6) + xx] : 0.f;
  }
  __syncthreads();

  float iv[5][5];
  #pragma unroll
  for (int ky = 0; ky < 5; ky++)
    #pragma unroll
    for (int kx = 0; kx < 5; kx++) iv[ky][kx] = lv[ly + ky][x + kx];

  const int y = y0t + ly;
  float vmax = -1e30f;
  #pragma unroll
  for (int a = 0; a < 10; a++) {
    float q = 0.f;
    #pragma unroll
    for (int ky = 0; ky < 5; ky++)
      #pragma unroll
      for (int kx = 0; kx < 5; kx++)
        q = fmaf(iv[ky][kx], qw[a * 25 + ky * 5 + kx], q);
    qr[((size_t)(b * 10 + a) << 12) + (y << 6) + x] = q;
    vmax = fmaxf(vmax, q);
  }
  v0[((size_t)b << 12) + (y << 6) + x] = vmax;
}

// ---------------- VI step: v' = max_a (qr + conv5x5(v, w)) -----------------
__global__ __launch_bounds__(256) void vi_step(
    const float* __restrict__ vin, const float* __restrict__ qr,
    const float* __restrict__ ww, float* __restrict__ vout)
{
  const int tile = blockIdx.x;
  const int b    = tile >> 4;
  const int y0t  = (tile & 15) * 4;
  const int tid  = threadIdx.x;
  const int x    = tid & 63;
  const int ly   = tid >> 6;

  __shared__ float lv[8][68];
  for (int idx = tid; idx < 8 * 68; idx += 256) {
    int rr = idx / 68, c = idx - rr * 68;
    int yy = y0t + rr - 2, xx = c - 2;
    lv[rr][c] = (yy >= 0 && yy < 64 && xx >= 0 && xx < 64)
                    ? vin[((size_t)b << 12) + (yy << 6) + xx] : 0.f;
  }
  __syncthreads();

  float iv[5][5];
  #pragma unroll
  for (int ky = 0; ky < 5; ky++)
    #pragma unroll
    for (int kx = 0; kx < 5; kx++) iv[ky][kx] = lv[ly + ky][x + kx];

  const int y = y0t + ly;
  float vmax = -1e30f;
  #pragma unroll
  for (int a = 0; a < 10; a++) {
    float q = qr[((size_t)(b * 10 + a) << 12) + (y << 6) + x];
    #pragma unroll
    for (int ky = 0; ky < 5; ky++)
      #pragma unroll
      for (int kx = 0; kx < 5; kx++)
        q = fmaf(iv[ky][kx], ww[a * 25 + ky * 5 + kx], q);
    vmax = fmaxf(vmax, q);
  }
  vout[((size_t)b << 12) + (y << 6) + x] = vmax;
}

// ---------------- critic ---------------------------------------------------
__global__ __launch_bounds__(256) void critic_k(
    const float* __restrict__ v, const float* __restrict__ cvw,
    const float* __restrict__ cvb, float* __restrict__ out)
{
  const int b = blockIdx.x;
  const int tid = threadIdx.x;
  const float4* pv = (const float4*)(v + ((size_t)b << 12));
  const float4* pw = (const float4*)cvw;
  float s = 0.f;
  #pragma unroll
  for (int i = 0; i < 4; i++) {
    float4 a = pv[tid + 256 * i];
    float4 w = pw[tid + 256 * i];
    s += a.x * w.x + a.y * w.y + a.z * w.z + a.w * w.w;
  }
  s = wave_sum(s);
  __shared__ float ls[4];
  const int w = tid >> 6;
  if ((tid & 63) == 0) ls[w] = s;
  __syncthreads();
  if (tid == 0) out[b] = ls[0] + ls[1] + ls[2] + ls[3] + cvb[0];
}

// ---------------- action MLP ----------------------------------------------
__global__ __launch_bounds__(128) void action_k(
    const float* __restrict__ obs, const float* __restrict__ fc1w,
    const float* __restrict__ fc1b, const float* __restrict__ fc2w,
    const float* __restrict__ fc2b, float* __restrict__ out)
{
  const int b = blockIdx.x;
  const int j = threadIdx.x;
  __shared__ float ob[24];
  __shared__ float h[100];
  if (j < 24) ob[j] = obs[b * 24 + j];
  __syncthreads();
  if (j < 100) {
    float s = fc1b[j];
    #pragma unroll
    for (int k = 0; k < 24; k++) s = fmaf(ob[k], fc1w[j * 24 + k], s);
    h[j] = fmaxf(s, 0.f);
  }
  __syncthreads();
  if (j < 10) {
    float s = fc2b[j];
    for (int k = 0; k < 100; k++) s = fmaf(h[k], fc2w[j * 100 + k], s);
    out[128 + b * 10 + j] = fmaxf(s, 0.f);
  }
}

// ---------------------------------------------------------------------------
extern "C" void kernel_launch(void* const* d_in, const int* in_sizes, int n_in,
                              void* d_out, int out_size, void* d_ws,
                              size_t ws_size, hipStream_t stream)
{
  const float* X     = (const float*)d_in[0];
  const float* obs   = (const float*)d_in[1];
  const float* h1_w  = (const float*)d_in[2];
  const float* h1_b  = (const float*)d_in[3];
  const float* g1    = (const float*)d_in[4];
  const float* b1    = (const float*)d_in[5];
  const float* h2_w  = (const float*)d_in[6];
  const float* h2_b  = (const float*)d_in[7];
  const float* g2    = (const float*)d_in[8];
  const float* b2    = (const float*)d_in[9];
  const float* h3_w  = (const float*)d_in[10];
  const float* h3_b  = (const float*)d_in[11];
  const float* g3    = (const float*)d_in[12];
  const float* b3    = (const float*)d_in[13];
  const float* r_w   = (const float*)d_in[14];
  const float* q_w   = (const float*)d_in[15];
  const float* w_vi  = (const float*)d_in[16];
  const float* fc1_w = (const float*)d_in[17];
  const float* fc1_b = (const float*)d_in[18];
  const float* fc2_w = (const float*)d_in[19];
  const float* fc2_b = (const float*)d_in[20];
  const float* cv_w  = (const float*)d_in[21];
  const float* cv_b  = (const float*)d_in[22];
  // K (d_in[23]) fixed to 36 by setup; loop count is compile-time.

  char* ws = (char*)d_ws;
  unsigned short* t2  = (unsigned short*)ws;                       // 125,829,120 B
  unsigned short* t3  = (unsigned short*)(ws + 125829120ull);      // 109,051,904 B
  unsigned short* W2h = (unsigned short*)(ws + 234881024ull);      //     387,072 B
  unsigned short* W2l = (unsigned short*)(ws + 235268096ull);      //     387,072 B
  unsigned short* W3h = (unsigned short*)(ws + 235655168ull);      //     313,344 B
  unsigned short* W3l = (unsigned short*)(ws + 235968512ull);      //     313,344 B
  float*          ST  = (float*)         (ws + 236281856ull);      //       5,920 B
  float* S1 = ST +    0; float* Q1 = ST +  150; float* A1 = ST +  300; float* B1 = ST +  450;
  float* S2 = ST +  600; float* Q2 = ST +  720; float* A2 = ST +  840; float* B2 = ST +  960;
  float* S3 = ST + 1080; float* Q3 = ST + 1180; float* A3 = ST + 1280; float* B3 = ST + 1380;
  // VI fp32 buffers aliased over dead t2 region
  float* r  = (float*)ws;          // 524,288 f
  float* qr = r + 524288;          // 5,242,880 f
  float* vA = qr + 5242880;        // 524,288 f
  float* vB = vA + 524288;         // 524,288 f

  hipMemsetAsync(ST, 0, 1480 * sizeof(float), stream);

  repack_w<120, 150, 168><<<756, 256, 0, stream>>>(h2_w, W2h, W2l);
  repack_w<100, 120, 136><<<612, 256, 0, stream>>>(h3_w, W3h, W3l);

  conv1_stats<<<dim3(1024, 10), 256, 0, stream>>>(X, h1_w, h1_b, S1, Q1);
  bn_finalize<150><<<1, 256, 0, stream>>>(S1, Q1, g1, b1, A1, B1);

  conv2_mfma<<<dim3(8192, 2), 256, 0, stream>>>(X, h1_w, h1_b, A1, B1, W2h, W2l, h2_b, t2);
  nhwc_stats<120, 15, 120><<<1024, 256, 0, stream>>>(t2, S2, Q2);
  bn_finalize<120><<<1, 256, 0, stream>>>(S2, Q2, g2, b2, A2, B2);

  conv3_mfma<<<dim3(8192, 2), 256, 0, stream>>>(t2, A2, B2, W3h, W3l, h3_b, t3);
  nhwc_stats<104, 13, 100><<<1024, 256, 0, stream>>>(t3, S3, Q3);
  bn_finalize<100><<<1, 256, 0, stream>>>(S3, Q3, g3, b3, A3, B3);

  bn3_reduce_r<<<2048, 256, 0, stream>>>(t3, A3, B3, r_w, r);

  qr_init<<<2048, 256, 0, stream>>>(r, q_w, qr, vA);
  for (int i = 0; i < 36; i++) {
    const float* vin = (i & 1) ? vB : vA;
    float* vout      = (i & 1) ? vA : vB;
    vi_step<<<2048, 256, 0, stream>>>(vin, qr, w_vi, vout);
  }

  float* out = (float*)d_out;
  critic_k<<<128, 256, 0, stream>>>(vA, cv_w, cv_b, out);
  action_k<<<128, 128, 0, stream>>>(obs, fc1_w, fc1_b, fc2_w, fc2_b, out);
}

// Round 7
// 1887.484 us; speedup vs baseline: 5.9323x; 1.4931x over previous
//
#include <hip/hip_runtime.h>

// ---------------------------------------------------------------------------
// VIN on MI355X (gfx950). B=128, H=W=64, C: 2 -> 150 -> 120 -> 100, q=10, K=36.
// R7: conv2/conv3 MFMA implicit GEMM restructured:
//   - M=256 px tile (16x16), 4 waves x (M64 x N64), acc 4x4 frags
//   - ci chunked (32/chunk = one MFMA K), all 9 positions staged per round
//   - LDS strides padded to 34 ushorts (17 words, odd -> conflict-free)
//   - split-bf16 weights (hi+lo) kept for fp32-accurate weights
// NHWC bf16 t2 [524288][120], t3 [524288][104]; VI fp32 aliased over dead t2.
// ---------------------------------------------------------------------------

#define NHW 524288.0f

typedef __attribute__((ext_vector_type(8))) short v8s;
typedef __attribute__((ext_vector_type(4))) float v4f;

static __device__ __forceinline__ float bf2f(unsigned short u) {
  return __uint_as_float(((unsigned int)u) << 16);
}
static __device__ __forceinline__ unsigned short f2bf(float f) {
  unsigned int x = __float_as_uint(f);
  return (unsigned short)((x + 0x7fffu + ((x >> 16) & 1u)) >> 16);  // RNE
}
static __device__ __forceinline__ float wave_sum(float s) {
  #pragma unroll
  for (int off = 32; off > 0; off >>= 1) s += __shfl_down(s, off, 64);
  return s;
}

// -------- weight repack + hi/lo split: w[co][ci][3][3] -> [9][128][CIP] ----
template <int CO, int CI, int CIP>
__global__ __launch_bounds__(256) void repack_w(
    const float* __restrict__ w, unsigned short* __restrict__ Whi,
    unsigned short* __restrict__ Wlo)
{
  int i = blockIdx.x * 256 + threadIdx.x;
  const int total = 9 * 128 * CIP;
  if (i >= total) return;
  int pos = i / (128 * CIP);
  int rem = i - pos * (128 * CIP);
  int co  = rem / CIP;
  int ci  = rem - co * CIP;
  float v = (co < CO && ci < CI) ? w[(co * CI + ci) * 9 + pos] : 0.f;
  unsigned short hi = f2bf(v);
  Whi[i] = hi;
  Wlo[i] = f2bf(v - bf2f(hi));
}

// ---------------- conv1 (2->150) stats-only, LDS-accumulated ---------------
__global__ __launch_bounds__(256) void conv1_stats(
    const float* __restrict__ X, const float* __restrict__ w1,
    const float* __restrict__ b1, float* __restrict__ S, float* __restrict__ Q)
{
  const int tile = blockIdx.x;             // 128*8
  const int b    = tile >> 3;
  const int y0t  = (tile & 7) * 8;
  const int co0  = blockIdx.y * 15;        // 10 groups of 15
  const int tid  = threadIdx.x;
  const int x    = tid & 63;
  const int ly0  = (tid >> 6) * 2;

  __shared__ float lin[2][10][66];
  __shared__ float ss[15], qq[15];
  if (tid < 15) { ss[tid] = 0.f; qq[tid] = 0.f; }
  for (int idx = tid; idx < 2 * 10 * 66; idx += 256) {
    int cc = idx / 660, rem = idx - cc * 660;
    int rr = rem / 66,  c   = rem - rr * 66;
    int yy = y0t + rr - 1, xx = c - 1;
    lin[cc][rr][c] = (yy >= 0 && yy < 64 && xx >= 0 && xx < 64)
                         ? X[((size_t)(b * 2 + cc) << 12) + (yy << 6) + xx] : 0.f;
  }
  __syncthreads();

  float iv[2][4][3];
  #pragma unroll
  for (int cc = 0; cc < 2; cc++)
    #pragma unroll
    for (int r = 0; r < 4; r++)
      #pragma unroll
      for (int c = 0; c < 3; c++) iv[cc][r][c] = lin[cc][ly0 + r][x + c];

  #pragma unroll
  for (int co = 0; co < 15; co++) {
    const float* w9 = w1 + (size_t)(co0 + co) * 18;
    float a0 = 0.f, a1 = 0.f;
    #pragma unroll
    for (int cc = 0; cc < 2; cc++)
      #pragma unroll
      for (int ky = 0; ky < 3; ky++)
        #pragma unroll
        for (int kx = 0; kx < 3; kx++) {
          float wv = w9[cc * 9 + ky * 3 + kx];
          a0 = fmaf(iv[cc][ky][kx],     wv, a0);
          a1 = fmaf(iv[cc][ky + 1][kx], wv, a1);
        }
    float bz = b1[co0 + co];
    float t0 = a0 + bz, t1 = a1 + bz;
    float s  = wave_sum(t0 + t1);
    float q  = wave_sum(t0 * t0 + t1 * t1);
    if ((tid & 63) == 0) { atomicAdd(&ss[co], s); atomicAdd(&qq[co], q); }
  }
  __syncthreads();
  if (tid < 15) {
    atomicAdd(&S[co0 + tid], ss[tid]);
    atomicAdd(&Q[co0 + tid], qq[tid]);
  }
}

// ---------------- BN finalize ----------------------------------------------
template <int C>
__global__ void bn_finalize(const float* __restrict__ S, const float* __restrict__ Q,
                            const float* __restrict__ g, const float* __restrict__ be,
                            float* __restrict__ A, float* __restrict__ Bs)
{
  int c = threadIdx.x;
  if (c < C) {
    const float invN = 1.f / NHW;
    float m   = S[c] * invN;
    float var = fmaxf(Q[c] * invN - m * m, 0.f);
    float sc  = g[c] * rsqrtf(var + 1e-5f);
    A[c]  = sc;
    Bs[c] = be[c] - m * sc;
  }
}

// ---------------- conv2 MFMA: 256px x 64co tile, ci-chunked ----------------
// grid (2048, 2): bx -> b, 16x16 px tile; by = co-group (64 co).
__global__ __launch_bounds__(256, 2) void conv2_mfma(
    const float* __restrict__ X,  const float* __restrict__ w1,
    const float* __restrict__ b1f, const float* __restrict__ A1,
    const float* __restrict__ B1, const unsigned short* __restrict__ W2h,
    const unsigned short* __restrict__ W2l,
    const float* __restrict__ b2, unsigned short* __restrict__ t2)
{
  const int bx   = blockIdx.x;
  const int b    = bx >> 4;
  const int t16  = bx & 15;
  const int y0   = (t16 >> 2) * 16;
  const int x0   = (t16 & 3) * 16;
  const int cg   = blockIdx.y;
  const int tid  = threadIdx.x;
  const int lane = tid & 63;
  const int wid  = __builtin_amdgcn_readfirstlane(tid >> 6);
  const int ln   = lane & 15;
  const int quad = (lane >> 4) * 8;       // ushort offset within 32-ci chunk

  __shared__ __align__(16) float Xs[2][20][20];
  __shared__ float w1s[2700];
  __shared__ float A1s[150], B1s[150], b1s[150], b2s[64];
  __shared__ __align__(16) unsigned short Atile[324 * 34];   // halo px x ci-chunk
  __shared__ __align__(16) unsigned short Btile[9 * 64 * 34]; // pos x co x ci-chunk

  for (int i = tid; i < 2700; i += 256) w1s[i] = w1[i];
  for (int i = tid; i < 150; i += 256) { A1s[i] = A1[i]; B1s[i] = B1[i]; b1s[i] = b1f[i]; }
  if (tid < 64) { int co = cg * 64 + tid; b2s[tid] = (co < 120) ? b2[co] : 0.f; }
  for (int i = tid; i < 800; i += 256) {
    int c2 = i / 400, rem = i - c2 * 400;
    int rr = rem / 20, cc = rem - rr * 20;
    int gy = y0 - 2 + rr, gx = x0 - 2 + cc;
    Xs[c2][rr][cc] = (gy >= 0 && gy < 64 && gx >= 0 && gx < 64)
                         ? X[((size_t)(b * 2 + c2) << 12) + (gy << 6) + gx] : 0.f;
  }

  v4f acc[4][4];
  #pragma unroll
  for (int i = 0; i < 4; i++)
    #pragma unroll
    for (int j = 0; j < 4; j++) acc[i][j] = (v4f){0.f, 0.f, 0.f, 0.f};

  for (int r = 0; r < 10; r++) {          // 5 ci-chunks x {hi, lo}
    const int chunk = r >> 1, half = r & 1;
    __syncthreads();                      // prior round's tile reads done
    if (half == 0) {
      // stage A chunk: h1 = relu(bn1(conv1(X))) for ci in [32c, 32c+32)
      const int ci_loc = tid & 31;
      const int ci = chunk * 32 + ci_loc;
      const bool live = (ci < 150);
      float wv[18], sc = 0.f, sh = 0.f, bz = 0.f;
      if (live) {
        #pragma unroll
        for (int k = 0; k < 18; k++) wv[k] = w1s[ci * 18 + k];
        sc = A1s[ci]; sh = B1s[ci]; bz = b1s[ci];
      }
      for (int pass = 0; pass < 41; pass++) {
        int p = pass * 8 + (tid >> 5);
        if (p < 324) {
          float v = 0.f;
          if (live) {
            int pr = p / 18, pc = p - pr * 18;
            int hy = y0 - 1 + pr, hx = x0 - 1 + pc;
            if (hy >= 0 && hy < 64 && hx >= 0 && hx < 64) {
              float a = bz;
              #pragma unroll
              for (int c2 = 0; c2 < 2; c2++)
                #pragma unroll
                for (int ky = 0; ky < 3; ky++)
                  #pragma unroll
                  for (int kx = 0; kx < 3; kx++)
                    a = fmaf(Xs[c2][pr + ky][pc + kx], wv[c2 * 9 + ky * 3 + kx], a);
              v = fmaxf(fmaf(a, sc, sh), 0.f);
            }
          }
          Atile[p * 34 + ci_loc] = f2bf(v);
        }
      }
    }
    // stage B chunk: all 9 positions, 64 co, 32 ci
    {
      const unsigned short* Wsrc = half ? W2l : W2h;
      for (int i = tid; i < 2304; i += 256) {
        int pos = i >> 8, rem = i & 255, co = rem >> 2, q = rem & 3;
        uint4 v = *(const uint4*)(Wsrc + (size_t)(pos * 128 + cg * 64 + co) * 160
                                  + chunk * 32 + q * 8);
        *(uint4*)(&Btile[(pos * 64 + co) * 34 + q * 8]) = v;
      }
    }
    __syncthreads();

    #pragma unroll
    for (int pos = 0; pos < 9; pos++) {
      const int ky = pos / 3, kx = pos - ky * 3;
      v8s bf[4];
      #pragma unroll
      for (int nj = 0; nj < 4; nj++)
        bf[nj] = *(const v8s*)(&Btile[(pos * 64 + nj * 16 + ln) * 34 + quad]);
      #pragma unroll
      for (int mi = 0; mi < 4; mi++) {
        v8s af = *(const v8s*)(&Atile[((wid * 4 + mi + ky) * 18 + ln + kx) * 34 + quad]);
        #pragma unroll
        for (int nj = 0; nj < 4; nj++)
          acc[mi][nj] = __builtin_amdgcn_mfma_f32_16x16x32_bf16(af, bf[nj], acc[mi][nj], 0, 0, 0);
      }
    }
  }
  __syncthreads();

  // epilogue: acc -> outs[256][68] (reuse Btile), bias, NHWC store
  unsigned short* outs = Btile;
  #pragma unroll
  for (int mi = 0; mi < 4; mi++)
    #pragma unroll
    for (int nj = 0; nj < 4; nj++) {
      int n = nj * 16 + ln;
      float bz = b2s[n];
      #pragma unroll
      for (int r2 = 0; r2 < 4; r2++) {
        int m = wid * 64 + mi * 16 + (lane >> 4) * 4 + r2;
        outs[m * 68 + n] = f2bf(acc[mi][nj][r2] + bz);
      }
    }
  __syncthreads();

  const int ng = cg ? 7 : 8;     // cg=1 -> co 64..119 (7 ushort8 groups)
  for (int i = tid; i < 256 * ng; i += 256) {
    int p = i / ng, g = i - p * ng;
    int gy = y0 + (p >> 4), gx = x0 + (p & 15);
    size_t gpx = ((size_t)b << 12) + (gy << 6) + gx;
    *(uint4*)(t2 + gpx * 120 + cg * 64 + g * 8) = *(const uint4*)(&outs[p * 68 + g * 8]);
  }
}

// ---------------- conv3 MFMA: 256px x 64co tile, ci-chunked ----------------
__global__ __launch_bounds__(256, 2) void conv3_mfma(
    const unsigned short* __restrict__ t2, const float* __restrict__ A2,
    const float* __restrict__ B2, const unsigned short* __restrict__ W3h,
    const unsigned short* __restrict__ W3l,
    const float* __restrict__ b3, unsigned short* __restrict__ t3)
{
  const int bx   = blockIdx.x;
  const int b    = bx >> 4;
  const int t16  = bx & 15;
  const int y0   = (t16 >> 2) * 16;
  const int x0   = (t16 & 3) * 16;
  const int cg   = blockIdx.y;
  const int tid  = threadIdx.x;
  const int lane = tid & 63;
  const int wid  = __builtin_amdgcn_readfirstlane(tid >> 6);
  const int ln   = lane & 15;
  const int quad = (lane >> 4) * 8;

  __shared__ float A2s[120], B2s[120], b3s[64];
  __shared__ __align__(16) unsigned short Atile[324 * 34];
  __shared__ __align__(16) unsigned short Btile[9 * 64 * 34];

  for (int i = tid; i < 120; i += 256) { A2s[i] = A2[i]; B2s[i] = B2[i]; }
  if (tid < 64) { int co = cg * 64 + tid; b3s[tid] = (co < 100) ? b3[co] : 0.f; }

  v4f acc[4][4];
  #pragma unroll
  for (int i = 0; i < 4; i++)
    #pragma unroll
    for (int j = 0; j < 4; j++) acc[i][j] = (v4f){0.f, 0.f, 0.f, 0.f};

  for (int r = 0; r < 8; r++) {           // 4 ci-chunks x {hi, lo}
    const int chunk = r >> 1, half = r & 1;
    __syncthreads();
    if (half == 0) {
      // stage A chunk: BN2+ReLU(t2) halo, ci in [32c, 32c+32)
      const int ci0 = chunk * 32;
      const int ngr = (chunk == 3) ? 3 : 4;    // real uint4 groups (ci<120)
      for (int i = tid; i < 1296; i += 256) {  // 324 px x 4 groups
        int p = i >> 2, g = i & 3;
        int pr = p / 18, pc = p - pr * 18;
        int hy = y0 - 1 + pr, hx = x0 - 1 + pc;
        union { uint4 v; unsigned short u[8]; } ov;
        ov.v = (uint4){0, 0, 0, 0};
        if (g < ngr && hy >= 0 && hy < 64 && hx >= 0 && hx < 64) {
          size_t gpx = ((size_t)b << 12) + (hy << 6) + hx;
          union { uint4 v; unsigned short u[8]; } in;
          in.v = *(const uint4*)(t2 + gpx * 120 + ci0 + g * 8);
          #pragma unroll
          for (int j = 0; j < 8; j++) {
            int ci = ci0 + g * 8 + j;
            ov.u[j] = f2bf(fmaxf(fmaf(bf2f(in.u[j]), A2s[ci], B2s[ci]), 0.f));
          }
        }
        *(uint4*)(&Atile[p * 34 + g * 8]) = ov.v;
      }
    }
    {
      const unsigned short* Wsrc = half ? W3l : W3h;
      for (int i = tid; i < 2304; i += 256) {
        int pos = i >> 8, rem = i & 255, co = rem >> 2, q = rem & 3;
        uint4 v = *(const uint4*)(Wsrc + (size_t)(pos * 128 + cg * 64 + co) * 128
                                  + chunk * 32 + q * 8);
        *(uint4*)(&Btile[(pos * 64 + co) * 34 + q * 8]) = v;
      }
    }
    __syncthreads();

    #pragma unroll
    for (int pos = 0; pos < 9; pos++) {
      const int ky = pos / 3, kx = pos - ky * 3;
      v8s bf[4];
      #pragma unroll
      for (int nj = 0; nj < 4; nj++)
        bf[nj] = *(const v8s*)(&Btile[(pos * 64 + nj * 16 + ln) * 34 + quad]);
      #pragma unroll
      for (int mi = 0; mi < 4; mi++) {
        v8s af = *(const v8s*)(&Atile[((wid * 4 + mi + ky) * 18 + ln + kx) * 34 + quad]);
        #pragma unroll
        for (int nj = 0; nj < 4; nj++)
          acc[mi][nj] = __builtin_amdgcn_mfma_f32_16x16x32_bf16(af, bf[nj], acc[mi][nj], 0, 0, 0);
      }
    }
  }
  __syncthreads();

  unsigned short* outs = Btile;   // [256][68]
  #pragma unroll
  for (int mi = 0; mi < 4; mi++)
    #pragma unroll
    for (int nj = 0; nj < 4; nj++) {
      int n = nj * 16 + ln;
      float bz = b3s[n];          // 0 for co>=100 (weights also 0 -> stores 0)
      #pragma unroll
      for (int r2 = 0; r2 < 4; r2++) {
        int m = wid * 64 + mi * 16 + (lane >> 4) * 4 + r2;
        outs[m * 68 + n] = f2bf(acc[mi][nj][r2] + bz);
      }
    }
  __syncthreads();

  const int ng = cg ? 5 : 8;      // cg=1 -> co 64..103 (100..103 zeros)
  for (int i = tid; i < 256 * ng; i += 256) {
    int p = i / ng, g = i - p * ng;
    int gy = y0 + (p >> 4), gx = x0 + (p & 15);
    size_t gpx = ((size_t)b << 12) + (gy << 6) + gx;
    *(uint4*)(t3 + gpx * 104 + cg * 64 + g * 8) = *(const uint4*)(&outs[p * 68 + g * 8]);
  }
}

// ---------------- per-channel sums over NHWC bf16 tensor -------------------
template <int ST, int NG, int C>
__global__ __launch_bounds__(256) void nhwc_stats(
    const unsigned short* __restrict__ t, float* __restrict__ S, float* __restrict__ Q)
{
  const int tid = threadIdx.x;
  const int g   = tid & 15;
  const int pl  = tid >> 4;
  const bool valid = (g < NG);
  const int px0 = blockIdx.x * 512;

  __shared__ float ss[128], qq[128];
  for (int i = tid; i < 128; i += 256) { ss[i] = 0.f; qq[i] = 0.f; }
  __syncthreads();

  float s8[8], q8[8];
  #pragma unroll
  for (int j = 0; j < 8; j++) { s8[j] = 0.f; q8[j] = 0.f; }

  if (valid) {
    for (int it = 0; it < 32; it++) {
      size_t px = px0 + it * 16 + pl;
      union { uint4 v; unsigned short u[8]; } in;
      in.v = *(const uint4*)(t + px * ST + g * 8);
      #pragma unroll
      for (int j = 0; j < 8; j++) {
        float v = bf2f(in.u[j]);
        s8[j] += v;
        q8[j] += v * v;
      }
    }
    #pragma unroll
    for (int j = 0; j < 8; j++) {
      atomicAdd(&ss[g * 8 + j], s8[j]);
      atomicAdd(&qq[g * 8 + j], q8[j]);
    }
  }
  __syncthreads();
  if (tid < C) {
    atomicAdd(&S[tid], ss[tid]);
    atomicAdd(&Q[tid], qq[tid]);
  }
}

// ---------------- BN3+ReLU+1x1 reward reduce over NHWC t3 ------------------
__global__ __launch_bounds__(256) void bn3_reduce_r(
    const unsigned short* __restrict__ t3, const float* __restrict__ A3,
    const float* __restrict__ B3, const float* __restrict__ rw,
    float* __restrict__ r)
{
  __shared__ float A3s[104], B3s[104], rws[104];
  const int tid = threadIdx.x;
  for (int i = tid; i < 104; i += 256) {
    bool v = (i < 100);
    A3s[i] = v ? A3[i] : 0.f;
    B3s[i] = v ? B3[i] : 0.f;
    rws[i] = v ? rw[i] : 0.f;
  }
  __syncthreads();

  size_t px = (size_t)blockIdx.x * 256 + tid;
  const unsigned short* p = t3 + px * 104;
  float a = 0.f;
  #pragma unroll
  for (int gq = 0; gq < 13; gq++) {
    union { uint4 v; unsigned short u[8]; } in;
    in.v = *(const uint4*)(p + gq * 8);
    #pragma unroll
    for (int j = 0; j < 8; j++) {
      int ci = gq * 8 + j;
      a = fmaf(fmaxf(fmaf(bf2f(in.u[j]), A3s[ci], B3s[ci]), 0.f), rws[ci], a);
    }
  }
  r[px] = a;
}

// ---------------- qr = conv5x5(r, q_w); v0 = max_a qr ----------------------
__global__ __launch_bounds__(256) void qr_init(
    const float* __restrict__ r, const float* __restrict__ qw,
    float* __restrict__ qr, float* __restrict__ v0)
{
  const int tile = blockIdx.x;          // 128*16
  const int b    = tile >> 4;
  const int y0t  = (tile & 15) * 4;
  const int tid  = threadIdx.x;
  const int x    = tid & 63;
  const int ly   = tid >> 6;

  __shared__ float lv[8][68];
  for (int idx = tid; idx < 8 * 68; idx += 256) {
    int rr = idx / 68, c = idx - rr * 68;
    int yy = y0t + rr - 2, xx = c - 2;
    lv[rr][c] = (yy >= 0 && yy < 64 && xx >= 0 && xx < 64)
                    ? r[((size_t)b << 12) + (yy << 6) + xx] : 0.f;
  }
  __syncthreads();

  float iv[5][5];
  #pragma unroll
  for (int ky = 0; ky < 5; ky++)
    #pragma unroll
    for (int kx = 0; kx < 5; kx++) iv[ky][kx] = lv[ly + ky][x + kx];

  const int y = y0t + ly;
  float vmax = -1e30f;
  #pragma unroll
  for (int a = 0; a < 10; a++) {
    float q = 0.f;
    #pragma unroll
    for (int ky = 0; ky < 5; ky++)
      #pragma unroll
      for (int kx = 0; kx < 5; kx++)
        q = fmaf(iv[ky][kx], qw[a * 25 + ky * 5 + kx], q);
    qr[((size_t)(b * 10 + a) << 12) + (y << 6) + x] = q;
    vmax = fmaxf(vmax, q);
  }
  v0[((size_t)b << 12) + (y << 6) + x] = vmax;
}

// ---------------- VI step: v' = max_a (qr + conv5x5(v, w)) -----------------
__global__ __launch_bounds__(256) void vi_step(
    const float* __restrict__ vin, const float* __restrict__ qr,
    const float* __restrict__ ww, float* __restrict__ vout)
{
  const int tile = blockIdx.x;
  const int b    = tile >> 4;
  const int y0t  = (tile & 15) * 4;
  const int tid  = threadIdx.x;
  const int x    = tid & 63;
  const int ly   = tid >> 6;

  __shared__ float lv[8][68];
  for (int idx = tid; idx < 8 * 68; idx += 256) {
    int rr = idx / 68, c = idx - rr * 68;
    int yy = y0t + rr - 2, xx = c - 2;
    lv[rr][c] = (yy >= 0 && yy < 64 && xx >= 0 && xx < 64)
                    ? vin[((size_t)b << 12) + (yy << 6) + xx] : 0.f;
  }
  __syncthreads();

  float iv[5][5];
  #pragma unroll
  for (int ky = 0; ky < 5; ky++)
    #pragma unroll
    for (int kx = 0; kx < 5; kx++) iv[ky][kx] = lv[ly + ky][x + kx];

  const int y = y0t + ly;
  float vmax = -1e30f;
  #pragma unroll
  for (int a = 0; a < 10; a++) {
    float q = qr[((size_t)(b * 10 + a) << 12) + (y << 6) + x];
    #pragma unroll
    for (int ky = 0; ky < 5; ky++)
      #pragma unroll
      for (int kx = 0; kx < 5; kx++)
        q = fmaf(iv[ky][kx], ww[a * 25 + ky * 5 + kx], q);
    vmax = fmaxf(vmax, q);
  }
  vout[((size_t)b << 12) + (y << 6) + x] = vmax;
}

// ---------------- critic ---------------------------------------------------
__global__ __launch_bounds__(256) void critic_k(
    const float* __restrict__ v, const float* __restrict__ cvw,
    const float* __restrict__ cvb, float* __restrict__ out)
{
  const int b = blockIdx.x;
  const int tid = threadIdx.x;
  const float4* pv = (const float4*)(v + ((size_t)b << 12));
  const float4* pw = (const float4*)cvw;
  float s = 0.f;
  #pragma unroll
  for (int i = 0; i < 4; i++) {
    float4 a = pv[tid + 256 * i];
    float4 w = pw[tid + 256 * i];
    s += a.x * w.x + a.y * w.y + a.z * w.z + a.w * w.w;
  }
  s = wave_sum(s);
  __shared__ float ls[4];
  const int w = tid >> 6;
  if ((tid & 63) == 0) ls[w] = s;
  __syncthreads();
  if (tid == 0) out[b] = ls[0] + ls[1] + ls[2] + ls[3] + cvb[0];
}

// ---------------- action MLP ----------------------------------------------
__global__ __launch_bounds__(128) void action_k(
    const float* __restrict__ obs, const float* __restrict__ fc1w,
    const float* __restrict__ fc1b, const float* __restrict__ fc2w,
    const float* __restrict__ fc2b, float* __restrict__ out)
{
  const int b = blockIdx.x;
  const int j = threadIdx.x;
  __shared__ float ob[24];
  __shared__ float h[100];
  if (j < 24) ob[j] = obs[b * 24 + j];
  __syncthreads();
  if (j < 100) {
    float s = fc1b[j];
    #pragma unroll
    for (int k = 0; k < 24; k++) s = fmaf(ob[k], fc1w[j * 24 + k], s);
    h[j] = fmaxf(s, 0.f);
  }
  __syncthreads();
  if (j < 10) {
    float s = fc2b[j];
    for (int k = 0; k < 100; k++) s = fmaf(h[k], fc2w[j * 100 + k], s);
    out[128 + b * 10 + j] = fmaxf(s, 0.f);
  }
}

// ---------------------------------------------------------------------------
extern "C" void kernel_launch(void* const* d_in, const int* in_sizes, int n_in,
                              void* d_out, int out_size, void* d_ws,
                              size_t ws_size, hipStream_t stream)
{
  const float* X     = (const float*)d_in[0];
  const float* obs   = (const float*)d_in[1];
  const float* h1_w  = (const float*)d_in[2];
  const float* h1_b  = (const float*)d_in[3];
  const float* g1    = (const float*)d_in[4];
  const float* b1    = (const float*)d_in[5];
  const float* h2_w  = (const float*)d_in[6];
  const float* h2_b  = (const float*)d_in[7];
  const float* g2    = (const float*)d_in[8];
  const float* b2    = (const float*)d_in[9];
  const float* h3_w  = (const float*)d_in[10];
  const float* h3_b  = (const float*)d_in[11];
  const float* g3    = (const float*)d_in[12];
  const float* b3    = (const float*)d_in[13];
  const float* r_w   = (const float*)d_in[14];
  const float* q_w   = (const float*)d_in[15];
  const float* w_vi  = (const float*)d_in[16];
  const float* fc1_w = (const float*)d_in[17];
  const float* fc1_b = (const float*)d_in[18];
  const float* fc2_w = (const float*)d_in[19];
  const float* fc2_b = (const float*)d_in[20];
  const float* cv_w  = (const float*)d_in[21];
  const float* cv_b  = (const float*)d_in[22];
  // K (d_in[23]) fixed to 36 by setup; loop count is compile-time.

  char* ws = (char*)d_ws;
  unsigned short* t2  = (unsigned short*)ws;                       // 125,829,120 B
  unsigned short* t3  = (unsigned short*)(ws + 125829120ull);      // 109,051,904 B
  unsigned short* W2h = (unsigned short*)(ws + 234881024ull);      //     368,640 B
  unsigned short* W2l = (unsigned short*)(ws + 235249664ull);      //     368,640 B
  unsigned short* W3h = (unsigned short*)(ws + 235618304ull);      //     294,912 B
  unsigned short* W3l = (unsigned short*)(ws + 235913216ull);      //     294,912 B
  float*          ST  = (float*)         (ws + 236208128ull);      //       5,920 B
  float* S1 = ST +    0; float* Q1 = ST +  150; float* A1 = ST +  300; float* B1 = ST +  450;
  float* S2 = ST +  600; float* Q2 = ST +  720; float* A2 = ST +  840; float* B2 = ST +  960;
  float* S3 = ST + 1080; float* Q3 = ST + 1180; float* A3 = ST + 1280; float* B3 = ST + 1380;
  // VI fp32 buffers aliased over dead t2 region
  float* r  = (float*)ws;          // 524,288 f
  float* qr = r + 524288;          // 5,242,880 f
  float* vA = qr + 5242880;        // 524,288 f
  float* vB = vA + 524288;         // 524,288 f

  hipMemsetAsync(ST, 0, 1480 * sizeof(float), stream);

  repack_w<120, 150, 160><<<720, 256, 0, stream>>>(h2_w, W2h, W2l);
  repack_w<100, 120, 128><<<576, 256, 0, stream>>>(h3_w, W3h, W3l);

  conv1_stats<<<dim3(1024, 10), 256, 0, stream>>>(X, h1_w, h1_b, S1, Q1);
  bn_finalize<150><<<1, 256, 0, stream>>>(S1, Q1, g1, b1, A1, B1);

  conv2_mfma<<<dim3(2048, 2), 256, 0, stream>>>(X, h1_w, h1_b, A1, B1, W2h, W2l, h2_b, t2);
  nhwc_stats<120, 15, 120><<<1024, 256, 0, stream>>>(t2, S2, Q2);
  bn_finalize<120><<<1, 256, 0, stream>>>(S2, Q2, g2, b2, A2, B2);

  conv3_mfma<<<dim3(2048, 2), 256, 0, stream>>>(t2, A2, B2, W3h, W3l, h3_b, t3);
  nhwc_stats<104, 13, 100><<<1024, 256, 0, stream>>>(t3, S3, Q3);
  bn_finalize<100><<<1, 256, 0, stream>>>(S3, Q3, g3, b3, A3, B3);

  bn3_reduce_r<<<2048, 256, 0, stream>>>(t3, A3, B3, r_w, r);

  qr_init<<<2048, 256, 0, stream>>>(r, q_w, qr, vA);
  for (int i = 0; i < 36; i++) {
    const float* vin = (i & 1) ? vB : vA;
    float* vout      = (i & 1) ? vA : vB;
    vi_step<<<2048, 256, 0, stream>>>(vin, qr, w_vi, vout);
  }

  float* out = (float*)d_out;
  critic_k<<<128, 256, 0, stream>>>(vA, cv_w, cv_b, out);
  action_k<<<128, 128, 0, stream>>>(obs, fc1_w, fc1_b, fc2_w, fc2_b, out);
}

// Round 8
// 1547.027 us; speedup vs baseline: 7.2378x; 1.2201x over previous
//
#include <hip/hip_runtime.h>

// ---------------------------------------------------------------------------
// VIN on MI355X (gfx950). B=128, H=W=64, C: 2 -> 150 -> 120 -> 100, q=10, K=36.
// R8: conv2/conv3 MFMA implicit GEMM:
//   - M=256 px tile (16x16), 4 waves x (M64 x N64), acc 4x4 frags
//   - ci chunked (32/chunk = one MFMA K), all 9 positions staged per round
//   - LDS strides 34 ushorts (17 words, odd -> balanced banks)
//   - PLAIN bf16 weights (lo-half dropped; halves MFMA + B staging)
//   - A-fragments register-cached (18 v8s/round; 25% fewer ds_read_b128)
// NHWC bf16 t2 [524288][120], t3 [524288][104]; VI fp32 aliased over dead t2.
// ---------------------------------------------------------------------------

#define NHW 524288.0f

typedef __attribute__((ext_vector_type(8))) short v8s;
typedef __attribute__((ext_vector_type(4))) float v4f;

static __device__ __forceinline__ float bf2f(unsigned short u) {
  return __uint_as_float(((unsigned int)u) << 16);
}
static __device__ __forceinline__ unsigned short f2bf(float f) {
  unsigned int x = __float_as_uint(f);
  return (unsigned short)((x + 0x7fffu + ((x >> 16) & 1u)) >> 16);  // RNE
}
static __device__ __forceinline__ float wave_sum(float s) {
  #pragma unroll
  for (int off = 32; off > 0; off >>= 1) s += __shfl_down(s, off, 64);
  return s;
}

// -------- weight repack: w[co][ci][3][3] f32 -> [9][128][CIP] bf16 ---------
template <int CO, int CI, int CIP>
__global__ __launch_bounds__(256) void repack_w(
    const float* __restrict__ w, unsigned short* __restrict__ Wp)
{
  int i = blockIdx.x * 256 + threadIdx.x;
  const int total = 9 * 128 * CIP;
  if (i >= total) return;
  int pos = i / (128 * CIP);
  int rem = i - pos * (128 * CIP);
  int co  = rem / CIP;
  int ci  = rem - co * CIP;
  float v = (co < CO && ci < CI) ? w[(co * CI + ci) * 9 + pos] : 0.f;
  Wp[i] = f2bf(v);
}

// ---------------- conv1 (2->150) stats-only, LDS-accumulated ---------------
__global__ __launch_bounds__(256) void conv1_stats(
    const float* __restrict__ X, const float* __restrict__ w1,
    const float* __restrict__ b1, float* __restrict__ S, float* __restrict__ Q)
{
  const int tile = blockIdx.x;             // 128*8
  const int b    = tile >> 3;
  const int y0t  = (tile & 7) * 8;
  const int co0  = blockIdx.y * 15;        // 10 groups of 15
  const int tid  = threadIdx.x;
  const int x    = tid & 63;
  const int ly0  = (tid >> 6) * 2;

  __shared__ float lin[2][10][66];
  __shared__ float ss[15], qq[15];
  if (tid < 15) { ss[tid] = 0.f; qq[tid] = 0.f; }
  for (int idx = tid; idx < 2 * 10 * 66; idx += 256) {
    int cc = idx / 660, rem = idx - cc * 660;
    int rr = rem / 66,  c   = rem - rr * 66;
    int yy = y0t + rr - 1, xx = c - 1;
    lin[cc][rr][c] = (yy >= 0 && yy < 64 && xx >= 0 && xx < 64)
                         ? X[((size_t)(b * 2 + cc) << 12) + (yy << 6) + xx] : 0.f;
  }
  __syncthreads();

  float iv[2][4][3];
  #pragma unroll
  for (int cc = 0; cc < 2; cc++)
    #pragma unroll
    for (int r = 0; r < 4; r++)
      #pragma unroll
      for (int c = 0; c < 3; c++) iv[cc][r][c] = lin[cc][ly0 + r][x + c];

  #pragma unroll
  for (int co = 0; co < 15; co++) {
    const float* w9 = w1 + (size_t)(co0 + co) * 18;
    float a0 = 0.f, a1 = 0.f;
    #pragma unroll
    for (int cc = 0; cc < 2; cc++)
      #pragma unroll
      for (int ky = 0; ky < 3; ky++)
        #pragma unroll
        for (int kx = 0; kx < 3; kx++) {
          float wv = w9[cc * 9 + ky * 3 + kx];
          a0 = fmaf(iv[cc][ky][kx],     wv, a0);
          a1 = fmaf(iv[cc][ky + 1][kx], wv, a1);
        }
    float bz = b1[co0 + co];
    float t0 = a0 + bz, t1 = a1 + bz;
    float s  = wave_sum(t0 + t1);
    float q  = wave_sum(t0 * t0 + t1 * t1);
    if ((tid & 63) == 0) { atomicAdd(&ss[co], s); atomicAdd(&qq[co], q); }
  }
  __syncthreads();
  if (tid < 15) {
    atomicAdd(&S[co0 + tid], ss[tid]);
    atomicAdd(&Q[co0 + tid], qq[tid]);
  }
}

// ---------------- BN finalize ----------------------------------------------
template <int C>
__global__ void bn_finalize(const float* __restrict__ S, const float* __restrict__ Q,
                            const float* __restrict__ g, const float* __restrict__ be,
                            float* __restrict__ A, float* __restrict__ Bs)
{
  int c = threadIdx.x;
  if (c < C) {
    const float invN = 1.f / NHW;
    float m   = S[c] * invN;
    float var = fmaxf(Q[c] * invN - m * m, 0.f);
    float sc  = g[c] * rsqrtf(var + 1e-5f);
    A[c]  = sc;
    Bs[c] = be[c] - m * sc;
  }
}

// ---------------- conv2 MFMA: 256px x 64co tile, ci-chunked ----------------
// grid (2048, 2): bx -> b, 16x16 px tile; by = co-group (64 co).
__global__ __launch_bounds__(256, 2) void conv2_mfma(
    const float* __restrict__ X,  const float* __restrict__ w1,
    const float* __restrict__ b1f, const float* __restrict__ A1,
    const float* __restrict__ B1, const unsigned short* __restrict__ W2p,
    const float* __restrict__ b2, unsigned short* __restrict__ t2)
{
  const int bx   = blockIdx.x;
  const int b    = bx >> 4;
  const int t16  = bx & 15;
  const int y0   = (t16 >> 2) * 16;
  const int x0   = (t16 & 3) * 16;
  const int cg   = blockIdx.y;
  const int tid  = threadIdx.x;
  const int lane = tid & 63;
  const int wid  = __builtin_amdgcn_readfirstlane(tid >> 6);
  const int ln   = lane & 15;
  const int quad = (lane >> 4) * 8;       // ushort offset within 32-ci chunk

  __shared__ __align__(16) float Xs[2][20][20];
  __shared__ float w1s[2700];
  __shared__ float A1s[150], B1s[150], b1s[150], b2s[64];
  __shared__ __align__(16) unsigned short Atile[324 * 34];    // halo px x ci-chunk
  __shared__ __align__(16) unsigned short Btile[9 * 64 * 34]; // pos x co x ci-chunk

  for (int i = tid; i < 2700; i += 256) w1s[i] = w1[i];
  for (int i = tid; i < 150; i += 256) { A1s[i] = A1[i]; B1s[i] = B1[i]; b1s[i] = b1f[i]; }
  if (tid < 64) { int co = cg * 64 + tid; b2s[tid] = (co < 120) ? b2[co] : 0.f; }
  for (int i = tid; i < 800; i += 256) {
    int c2 = i / 400, rem = i - c2 * 400;
    int rr = rem / 20, cc = rem - rr * 20;
    int gy = y0 - 2 + rr, gx = x0 - 2 + cc;
    Xs[c2][rr][cc] = (gy >= 0 && gy < 64 && gx >= 0 && gx < 64)
                         ? X[((size_t)(b * 2 + c2) << 12) + (gy << 6) + gx] : 0.f;
  }

  v4f acc[4][4];
  #pragma unroll
  for (int i = 0; i < 4; i++)
    #pragma unroll
    for (int j = 0; j < 4; j++) acc[i][j] = (v4f){0.f, 0.f, 0.f, 0.f};

  for (int chunk = 0; chunk < 5; chunk++) {
    __syncthreads();                      // prior round's tile reads done
    {
      // stage A chunk: h1 = relu(bn1(conv1(X))) for ci in [32c, 32c+32)
      const int ci_loc = tid & 31;
      const int ci = chunk * 32 + ci_loc;
      const bool live = (ci < 150);
      float wv[18], sc = 0.f, sh = 0.f, bz = 0.f;
      if (live) {
        #pragma unroll
        for (int k = 0; k < 18; k++) wv[k] = w1s[ci * 18 + k];
        sc = A1s[ci]; sh = B1s[ci]; bz = b1s[ci];
      }
      for (int pass = 0; pass < 41; pass++) {
        int p = pass * 8 + (tid >> 5);
        if (p < 324) {
          float v = 0.f;
          if (live) {
            int pr = p / 18, pc = p - pr * 18;
            int hy = y0 - 1 + pr, hx = x0 - 1 + pc;
            if (hy >= 0 && hy < 64 && hx >= 0 && hx < 64) {
              float a = bz;
              #pragma unroll
              for (int c2 = 0; c2 < 2; c2++)
                #pragma unroll
                for (int ky = 0; ky < 3; ky++)
                  #pragma unroll
                  for (int kx = 0; kx < 3; kx++)
                    a = fmaf(Xs[c2][pr + ky][pc + kx], wv[c2 * 9 + ky * 3 + kx], a);
              v = fmaxf(fmaf(a, sc, sh), 0.f);
            }
          }
          Atile[p * 34 + ci_loc] = f2bf(v);
        }
      }
    }
    // stage B chunk: all 9 positions, 64 co, 32 ci
    for (int i = tid; i < 2304; i += 256) {
      int pos = i >> 8, rem = i & 255, co = rem >> 2, q = rem & 3;
      uint4 v = *(const uint4*)(W2p + (size_t)(pos * 128 + cg * 64 + co) * 160
                                + chunk * 32 + q * 8);
      *(uint4*)(&Btile[(pos * 64 + co) * 34 + q * 8]) = v;
    }
    __syncthreads();

    // register-cache the 18 distinct A fragments for this round
    v8s afr[6][3];
    #pragma unroll
    for (int t = 0; t < 6; t++)
      #pragma unroll
      for (int kx = 0; kx < 3; kx++)
        afr[t][kx] = *(const v8s*)(&Atile[((wid * 4 + t) * 18 + ln + kx) * 34 + quad]);

    #pragma unroll
    for (int pos = 0; pos < 9; pos++) {
      const int ky = pos / 3, kx = pos - ky * 3;
      v8s bf[4];
      #pragma unroll
      for (int nj = 0; nj < 4; nj++)
        bf[nj] = *(const v8s*)(&Btile[(pos * 64 + nj * 16 + ln) * 34 + quad]);
      #pragma unroll
      for (int mi = 0; mi < 4; mi++) {
        #pragma unroll
        for (int nj = 0; nj < 4; nj++)
          acc[mi][nj] = __builtin_amdgcn_mfma_f32_16x16x32_bf16(
              afr[mi + ky][kx], bf[nj], acc[mi][nj], 0, 0, 0);
      }
    }
  }
  __syncthreads();

  // epilogue: acc -> outs[256][68] (reuse Btile), bias, NHWC store
  unsigned short* outs = Btile;
  #pragma unroll
  for (int mi = 0; mi < 4; mi++)
    #pragma unroll
    for (int nj = 0; nj < 4; nj++) {
      int n = nj * 16 + ln;
      float bz = b2s[n];
      #pragma unroll
      for (int r2 = 0; r2 < 4; r2++) {
        int m = wid * 64 + mi * 16 + (lane >> 4) * 4 + r2;
        outs[m * 68 + n] = f2bf(acc[mi][nj][r2] + bz);
      }
    }
  __syncthreads();

  const int ng = cg ? 7 : 8;     // cg=1 -> co 64..119 (7 ushort8 groups)
  for (int i = tid; i < 256 * ng; i += 256) {
    int p = i / ng, g = i - p * ng;
    int gy = y0 + (p >> 4), gx = x0 + (p & 15);
    size_t gpx = ((size_t)b << 12) + (gy << 6) + gx;
    *(uint4*)(t2 + gpx * 120 + cg * 64 + g * 8) = *(const uint4*)(&outs[p * 68 + g * 8]);
  }
}

// ---------------- conv3 MFMA: 256px x 64co tile, ci-chunked ----------------
__global__ __launch_bounds__(256, 2) void conv3_mfma(
    const unsigned short* __restrict__ t2, const float* __restrict__ A2,
    const float* __restrict__ B2, const unsigned short* __restrict__ W3p,
    const float* __restrict__ b3, unsigned short* __restrict__ t3)
{
  const int bx   = blockIdx.x;
  const int b    = bx >> 4;
  const int t16  = bx & 15;
  const int y0   = (t16 >> 2) * 16;
  const int x0   = (t16 & 3) * 16;
  const int cg   = blockIdx.y;
  const int tid  = threadIdx.x;
  const int lane = tid & 63;
  const int wid  = __builtin_amdgcn_readfirstlane(tid >> 6);
  const int ln   = lane & 15;
  const int quad = (lane >> 4) * 8;

  __shared__ float A2s[120], B2s[120], b3s[64];
  __shared__ __align__(16) unsigned short Atile[324 * 34];
  __shared__ __align__(16) unsigned short Btile[9 * 64 * 34];

  for (int i = tid; i < 120; i += 256) { A2s[i] = A2[i]; B2s[i] = B2[i]; }
  if (tid < 64) { int co = cg * 64 + tid; b3s[tid] = (co < 100) ? b3[co] : 0.f; }

  v4f acc[4][4];
  #pragma unroll
  for (int i = 0; i < 4; i++)
    #pragma unroll
    for (int j = 0; j < 4; j++) acc[i][j] = (v4f){0.f, 0.f, 0.f, 0.f};

  for (int chunk = 0; chunk < 4; chunk++) {
    __syncthreads();
    {
      // stage A chunk: BN2+ReLU(t2) halo, ci in [32c, 32c+32)
      const int ci0 = chunk * 32;
      const int ngr = (chunk == 3) ? 3 : 4;    // real uint4 groups (ci<120)
      for (int i = tid; i < 1296; i += 256) {  // 324 px x 4 groups
        int p = i >> 2, g = i & 3;
        int pr = p / 18, pc = p - pr * 18;
        int hy = y0 - 1 + pr, hx = x0 - 1 + pc;
        union { uint4 v; unsigned short u[8]; } ov;
        ov.v = (uint4){0, 0, 0, 0};
        if (g < ngr && hy >= 0 && hy < 64 && hx >= 0 && hx < 64) {
          size_t gpx = ((size_t)b << 12) + (hy << 6) + hx;
          union { uint4 v; unsigned short u[8]; } in;
          in.v = *(const uint4*)(t2 + gpx * 120 + ci0 + g * 8);
          #pragma unroll
          for (int j = 0; j < 8; j++) {
            int ci = ci0 + g * 8 + j;
            ov.u[j] = f2bf(fmaxf(fmaf(bf2f(in.u[j]), A2s[ci], B2s[ci]), 0.f));
          }
        }
        *(uint4*)(&Atile[p * 34 + g * 8]) = ov.v;
      }
    }
    for (int i = tid; i < 2304; i += 256) {
      int pos = i >> 8, rem = i & 255, co = rem >> 2, q = rem & 3;
      uint4 v = *(const uint4*)(W3p + (size_t)(pos * 128 + cg * 64 + co) * 128
                                + chunk * 32 + q * 8);
      *(uint4*)(&Btile[(pos * 64 + co) * 34 + q * 8]) = v;
    }
    __syncthreads();

    v8s afr[6][3];
    #pragma unroll
    for (int t = 0; t < 6; t++)
      #pragma unroll
      for (int kx = 0; kx < 3; kx++)
        afr[t][kx] = *(const v8s*)(&Atile[((wid * 4 + t) * 18 + ln + kx) * 34 + quad]);

    #pragma unroll
    for (int pos = 0; pos < 9; pos++) {
      const int ky = pos / 3, kx = pos - ky * 3;
      v8s bf[4];
      #pragma unroll
      for (int nj = 0; nj < 4; nj++)
        bf[nj] = *(const v8s*)(&Btile[(pos * 64 + nj * 16 + ln) * 34 + quad]);
      #pragma unroll
      for (int mi = 0; mi < 4; mi++) {
        #pragma unroll
        for (int nj = 0; nj < 4; nj++)
          acc[mi][nj] = __builtin_amdgcn_mfma_f32_16x16x32_bf16(
              afr[mi + ky][kx], bf[nj], acc[mi][nj], 0, 0, 0);
      }
    }
  }
  __syncthreads();

  unsigned short* outs = Btile;   // [256][68]
  #pragma unroll
  for (int mi = 0; mi < 4; mi++)
    #pragma unroll
    for (int nj = 0; nj < 4; nj++) {
      int n = nj * 16 + ln;
      float bz = b3s[n];          // 0 for co>=100 (weights also 0 -> stores 0)
      #pragma unroll
      for (int r2 = 0; r2 < 4; r2++) {
        int m = wid * 64 + mi * 16 + (lane >> 4) * 4 + r2;
        outs[m * 68 + n] = f2bf(acc[mi][nj][r2] + bz);
      }
    }
  __syncthreads();

  const int ng = cg ? 5 : 8;      // cg=1 -> co 64..103 (100..103 zeros)
  for (int i = tid; i < 256 * ng; i += 256) {
    int p = i / ng, g = i - p * ng;
    int gy = y0 + (p >> 4), gx = x0 + (p & 15);
    size_t gpx = ((size_t)b << 12) + (gy << 6) + gx;
    *(uint4*)(t3 + gpx * 104 + cg * 64 + g * 8) = *(const uint4*)(&outs[p * 68 + g * 8]);
  }
}

// ---------------- per-channel sums over NHWC bf16 tensor -------------------
template <int ST, int NG, int C>
__global__ __launch_bounds__(256) void nhwc_stats(
    const unsigned short* __restrict__ t, float* __restrict__ S, float* __restrict__ Q)
{
  const int tid = threadIdx.x;
  const int g   = tid & 15;
  const int pl  = tid >> 4;
  const bool valid = (g < NG);
  const int px0 = blockIdx.x * 512;

  __shared__ float ss[128], qq[128];
  for (int i = tid; i < 128; i += 256) { ss[i] = 0.f; qq[i] = 0.f; }
  __syncthreads();

  float s8[8], q8[8];
  #pragma unroll
  for (int j = 0; j < 8; j++) { s8[j] = 0.f; q8[j] = 0.f; }

  if (valid) {
    for (int it = 0; it < 32; it++) {
      size_t px = px0 + it * 16 + pl;
      union { uint4 v; unsigned short u[8]; } in;
      in.v = *(const uint4*)(t + px * ST + g * 8);
      #pragma unroll
      for (int j = 0; j < 8; j++) {
        float v = bf2f(in.u[j]);
        s8[j] += v;
        q8[j] += v * v;
      }
    }
    #pragma unroll
    for (int j = 0; j < 8; j++) {
      atomicAdd(&ss[g * 8 + j], s8[j]);
      atomicAdd(&qq[g * 8 + j], q8[j]);
    }
  }
  __syncthreads();
  if (tid < C) {
    atomicAdd(&S[tid], ss[tid]);
    atomicAdd(&Q[tid], qq[tid]);
  }
}

// ---------------- BN3+ReLU+1x1 reward reduce over NHWC t3 ------------------
__global__ __launch_bounds__(256) void bn3_reduce_r(
    const unsigned short* __restrict__ t3, const float* __restrict__ A3,
    const float* __restrict__ B3, const float* __restrict__ rw,
    float* __restrict__ r)
{
  __shared__ float A3s[104], B3s[104], rws[104];
  const int tid = threadIdx.x;
  for (int i = tid; i < 104; i += 256) {
    bool v = (i < 100);
    A3s[i] = v ? A3[i] : 0.f;
    B3s[i] = v ? B3[i] : 0.f;
    rws[i] = v ? rw[i] : 0.f;
  }
  __syncthreads();

  size_t px = (size_t)blockIdx.x * 256 + tid;
  const unsigned short* p = t3 + px * 104;
  float a = 0.f;
  #pragma unroll
  for (int gq = 0; gq < 13; gq++) {
    union { uint4 v; unsigned short u[8]; } in;
    in.v = *(const uint4*)(p + gq * 8);
    #pragma unroll
    for (int j = 0; j < 8; j++) {
      int ci = gq * 8 + j;
      a = fmaf(fmaxf(fmaf(bf2f(in.u[j]), A3s[ci], B3s[ci]), 0.f), rws[ci], a);
    }
  }
  r[px] = a;
}

// ---------------- qr = conv5x5(r, q_w); v0 = max_a qr ----------------------
__global__ __launch_bounds__(256) void qr_init(
    const float* __restrict__ r, const float* __restrict__ qw,
    float* __restrict__ qr, float* __restrict__ v0)
{
  const int tile = blockIdx.x;          // 128*16
  const int b    = tile >> 4;
  const int y0t  = (tile & 15) * 4;
  const int tid  = threadIdx.x;
  const int x    = tid & 63;
  const int ly   = tid >> 6;

  __shared__ float lv[8][68];
  for (int idx = tid; idx < 8 * 68; idx += 256) {
    int rr = idx / 68, c = idx - rr * 68;
    int yy = y0t + rr - 2, xx = c - 2;
    lv[rr][c] = (yy >= 0 && yy < 64 && xx >= 0 && xx < 64)
                    ? r[((size_t)b << 12) + (yy << 6) + xx] : 0.f;
  }
  __syncthreads();

  float iv[5][5];
  #pragma unroll
  for (int ky = 0; ky < 5; ky++)
    #pragma unroll
    for (int kx = 0; kx < 5; kx++) iv[ky][kx] = lv[ly + ky][x + kx];

  const int y = y0t + ly;
  float vmax = -1e30f;
  #pragma unroll
  for (int a = 0; a < 10; a++) {
    float q = 0.f;
    #pragma unroll
    for (int ky = 0; ky < 5; ky++)
      #pragma unroll
      for (int kx = 0; kx < 5; kx++)
        q = fmaf(iv[ky][kx], qw[a * 25 + ky * 5 + kx], q);
    qr[((size_t)(b * 10 + a) << 12) + (y << 6) + x] = q;
    vmax = fmaxf(vmax, q);
  }
  v0[((size_t)b << 12) + (y << 6) + x] = vmax;
}

// ---------------- VI step: v' = max_a (qr + conv5x5(v, w)) -----------------
__global__ __launch_bounds__(256) void vi_step(
    const float* __restrict__ vin, const float* __restrict__ qr,
    const float* __restrict__ ww, float* __restrict__ vout)
{
  const int tile = blockIdx.x;
  const int b    = tile >> 4;
  const int y0t  = (tile & 15) * 4;
  const int tid  = threadIdx.x;
  const int x    = tid & 63;
  const int ly   = tid >> 6;

  __shared__ float lv[8][68];
  for (int idx = tid; idx < 8 * 68; idx += 256) {
    int rr = idx / 68, c = idx - rr * 68;
    int yy = y0t + rr - 2, xx = c - 2;
    lv[rr][c] = (yy >= 0 && yy < 64 && xx >= 0 && xx < 64)
                    ? vin[((size_t)b << 12) + (yy << 6) + xx] : 0.f;
  }
  __syncthreads();

  float iv[5][5];
  #pragma unroll
  for (int ky = 0; ky < 5; ky++)
    #pragma unroll
    for (int kx = 0; kx < 5; kx++) iv[ky][kx] = lv[ly + ky][x + kx];

  const int y = y0t + ly;
  float vmax = -1e30f;
  #pragma unroll
  for (int a = 0; a < 10; a++) {
    float q = qr[((size_t)(b * 10 + a) << 12) + (y << 6) + x];
    #pragma unroll
    for (int ky = 0; ky < 5; ky++)
      #pragma unroll
      for (int kx = 0; kx < 5; kx++)
        q = fmaf(iv[ky][kx], ww[a * 25 + ky * 5 + kx], q);
    vmax = fmaxf(vmax, q);
  }
  vout[((size_t)b << 12) + (y << 6) + x] = vmax;
}

// ---------------- critic ---------------------------------------------------
__global__ __launch_bounds__(256) void critic_k(
    const float* __restrict__ v, const float* __restrict__ cvw,
    const float* __restrict__ cvb, float* __restrict__ out)
{
  const int b = blockIdx.x;
  const int tid = threadIdx.x;
  const float4* pv = (const float4*)(v + ((size_t)b << 12));
  const float4* pw = (const float4*)cvw;
  float s = 0.f;
  #pragma unroll
  for (int i = 0; i < 4; i++) {
    float4 a = pv[tid + 256 * i];
    float4 w = pw[tid + 256 * i];
    s += a.x * w.x + a.y * w.y + a.z * w.z + a.w * w.w;
  }
  s = wave_sum(s);
  __shared__ float ls[4];
  const int w = tid >> 6;
  if ((tid & 63) == 0) ls[w] = s;
  __syncthreads();
  if (tid == 0) out[b] = ls[0] + ls[1] + ls[2] + ls[3] + cvb[0];
}

// ---------------- action MLP ----------------------------------------------
__global__ __launch_bounds__(128) void action_k(
    const float* __restrict__ obs, const float* __restrict__ fc1w,
    const float* __restrict__ fc1b, const float* __restrict__ fc2w,
    const float* __restrict__ fc2b, float* __restrict__ out)
{
  const int b = blockIdx.x;
  const int j = threadIdx.x;
  __shared__ float ob[24];
  __shared__ float h[100];
  if (j < 24) ob[j] = obs[b * 24 + j];
  __syncthreads();
  if (j < 100) {
    float s = fc1b[j];
    #pragma unroll
    for (int k = 0; k < 24; k++) s = fmaf(ob[k], fc1w[j * 24 + k], s);
    h[j] = fmaxf(s, 0.f);
  }
  __syncthreads();
  if (j < 10) {
    float s = fc2b[j];
    for (int k = 0; k < 100; k++) s = fmaf(h[k], fc2w[j * 100 + k], s);
    out[128 + b * 10 + j] = fmaxf(s, 0.f);
  }
}

// ---------------------------------------------------------------------------
extern "C" void kernel_launch(void* const* d_in, const int* in_sizes, int n_in,
                              void* d_out, int out_size, void* d_ws,
                              size_t ws_size, hipStream_t stream)
{
  const float* X     = (const float*)d_in[0];
  const float* obs   = (const float*)d_in[1];
  const float* h1_w  = (const float*)d_in[2];
  const float* h1_b  = (const float*)d_in[3];
  const float* g1    = (const float*)d_in[4];
  const float* b1    = (const float*)d_in[5];
  const float* h2_w  = (const float*)d_in[6];
  const float* h2_b  = (const float*)d_in[7];
  const float* g2    = (const float*)d_in[8];
  const float* b2    = (const float*)d_in[9];
  const float* h3_w  = (const float*)d_in[10];
  const float* h3_b  = (const float*)d_in[11];
  const float* g3    = (const float*)d_in[12];
  const float* b3    = (const float*)d_in[13];
  const float* r_w   = (const float*)d_in[14];
  const float* q_w   = (const float*)d_in[15];
  const float* w_vi  = (const float*)d_in[16];
  const float* fc1_w = (const float*)d_in[17];
  const float* fc1_b = (const float*)d_in[18];
  const float* fc2_w = (const float*)d_in[19];
  const float* fc2_b = (const float*)d_in[20];
  const float* cv_w  = (const float*)d_in[21];
  const float* cv_b  = (const float*)d_in[22];
  // K (d_in[23]) fixed to 36 by setup; loop count is compile-time.

  char* ws = (char*)d_ws;
  unsigned short* t2  = (unsigned short*)ws;                       // 125,829,120 B
  unsigned short* t3  = (unsigned short*)(ws + 125829120ull);      // 109,051,904 B
  unsigned short* W2p = (unsigned short*)(ws + 234881024ull);      //     368,640 B
  unsigned short* W3p = (unsigned short*)(ws + 235249664ull);      //     294,912 B
  float*          ST  = (float*)         (ws + 235544576ull);      //       5,920 B
  float* S1 = ST +    0; float* Q1 = ST +  150; float* A1 = ST +  300; float* B1 = ST +  450;
  float* S2 = ST +  600; float* Q2 = ST +  720; float* A2 = ST +  840; float* B2 = ST +  960;
  float* S3 = ST + 1080; float* Q3 = ST + 1180; float* A3 = ST + 1280; float* B3 = ST + 1380;
  // VI fp32 buffers aliased over dead t2 region
  float* r  = (float*)ws;          // 524,288 f
  float* qr = r + 524288;          // 5,242,880 f
  float* vA = qr + 5242880;        // 524,288 f
  float* vB = vA + 524288;         // 524,288 f

  hipMemsetAsync(ST, 0, 1480 * sizeof(float), stream);

  repack_w<120, 150, 160><<<720, 256, 0, stream>>>(h2_w, W2p);
  repack_w<100, 120, 128><<<576, 256, 0, stream>>>(h3_w, W3p);

  conv1_stats<<<dim3(1024, 10), 256, 0, stream>>>(X, h1_w, h1_b, S1, Q1);
  bn_finalize<150><<<1, 256, 0, stream>>>(S1, Q1, g1, b1, A1, B1);

  conv2_mfma<<<dim3(2048, 2), 256, 0, stream>>>(X, h1_w, h1_b, A1, B1, W2p, h2_b, t2);
  nhwc_stats<120, 15, 120><<<1024, 256, 0, stream>>>(t2, S2, Q2);
  bn_finalize<120><<<1, 256, 0, stream>>>(S2, Q2, g2, b2, A2, B2);

  conv3_mfma<<<dim3(2048, 2), 256, 0, stream>>>(t2, A2, B2, W3p, h3_b, t3);
  nhwc_stats<104, 13, 100><<<1024, 256, 0, stream>>>(t3, S3, Q3);
  bn_finalize<100><<<1, 256, 0, stream>>>(S3, Q3, g3, b3, A3, B3);

  bn3_reduce_r<<<2048, 256, 0, stream>>>(t3, A3, B3, r_w, r);

  qr_init<<<2048, 256, 0, stream>>>(r, q_w, qr, vA);
  for (int i = 0; i < 36; i++) {
    const float* vin = (i & 1) ? vB : vA;
    float* vout      = (i & 1) ? vA : vB;
    vi_step<<<2048, 256, 0, stream>>>(vin, qr, w_vi, vout);
  }

  float* out = (float*)d_out;
  critic_k<<<128, 256, 0, stream>>>(vA, cv_w, cv_b, out);
  action_k<<<128, 128, 0, stream>>>(obs, fc1_w, fc1_b, fc2_w, fc2_b, out);
}

// Round 9
// 1318.717 us; speedup vs baseline: 8.4909x; 1.1731x over previous
//
#include <hip/hip_runtime.h>

// ---------------------------------------------------------------------------
// VIN on MI355X (gfx950). B=128, H=W=64, C: 2 -> 150 -> 120 -> 100, q=10, K=36.
// R9: conv2/conv3 MFMA implicit GEMM:
//   - one block = 256px x ALL 128 co (acc 4x8) -> A-staging done once (was 2x)
//   - B fragments read directly from global (L2-resident repacked weights);
//     no Btile LDS, no B-staging VALU, one fewer barrier per chunk
//   - ci chunked (32 = one MFMA K); A-frags register-cached (18 v8s/round)
//   - Atile stride 34 ushorts (odd word count -> balanced LDS banks)
// NHWC bf16 t2 [524288][120], t3 [524288][104]; VI fp32 aliased over dead t2.
// ---------------------------------------------------------------------------

#define NHW 524288.0f

typedef __attribute__((ext_vector_type(8))) short v8s;
typedef __attribute__((ext_vector_type(4))) float v4f;

static __device__ __forceinline__ float bf2f(unsigned short u) {
  return __uint_as_float(((unsigned int)u) << 16);
}
static __device__ __forceinline__ unsigned short f2bf(float f) {
  unsigned int x = __float_as_uint(f);
  return (unsigned short)((x + 0x7fffu + ((x >> 16) & 1u)) >> 16);  // RNE
}
static __device__ __forceinline__ float wave_sum(float s) {
  #pragma unroll
  for (int off = 32; off > 0; off >>= 1) s += __shfl_down(s, off, 64);
  return s;
}

// -------- weight repack: w[co][ci][3][3] f32 -> [9][128][CIP] bf16 ---------
template <int CO, int CI, int CIP>
__global__ __launch_bounds__(256) void repack_w(
    const float* __restrict__ w, unsigned short* __restrict__ Wp)
{
  int i = blockIdx.x * 256 + threadIdx.x;
  const int total = 9 * 128 * CIP;
  if (i >= total) return;
  int pos = i / (128 * CIP);
  int rem = i - pos * (128 * CIP);
  int co  = rem / CIP;
  int ci  = rem - co * CIP;
  float v = (co < CO && ci < CI) ? w[(co * CI + ci) * 9 + pos] : 0.f;
  Wp[i] = f2bf(v);
}

// ---------------- conv1 (2->150) stats-only, LDS-accumulated ---------------
__global__ __launch_bounds__(256) void conv1_stats(
    const float* __restrict__ X, const float* __restrict__ w1,
    const float* __restrict__ b1, float* __restrict__ S, float* __restrict__ Q)
{
  const int tile = blockIdx.x;             // 128*8
  const int b    = tile >> 3;
  const int y0t  = (tile & 7) * 8;
  const int co0  = blockIdx.y * 15;        // 10 groups of 15
  const int tid  = threadIdx.x;
  const int x    = tid & 63;
  const int ly0  = (tid >> 6) * 2;

  __shared__ float lin[2][10][66];
  __shared__ float ss[15], qq[15];
  if (tid < 15) { ss[tid] = 0.f; qq[tid] = 0.f; }
  for (int idx = tid; idx < 2 * 10 * 66; idx += 256) {
    int cc = idx / 660, rem = idx - cc * 660;
    int rr = rem / 66,  c   = rem - rr * 66;
    int yy = y0t + rr - 1, xx = c - 1;
    lin[cc][rr][c] = (yy >= 0 && yy < 64 && xx >= 0 && xx < 64)
                         ? X[((size_t)(b * 2 + cc) << 12) + (yy << 6) + xx] : 0.f;
  }
  __syncthreads();

  float iv[2][4][3];
  #pragma unroll
  for (int cc = 0; cc < 2; cc++)
    #pragma unroll
    for (int r = 0; r < 4; r++)
      #pragma unroll
      for (int c = 0; c < 3; c++) iv[cc][r][c] = lin[cc][ly0 + r][x + c];

  #pragma unroll
  for (int co = 0; co < 15; co++) {
    const float* w9 = w1 + (size_t)(co0 + co) * 18;
    float a0 = 0.f, a1 = 0.f;
    #pragma unroll
    for (int cc = 0; cc < 2; cc++)
      #pragma unroll
      for (int ky = 0; ky < 3; ky++)
        #pragma unroll
        for (int kx = 0; kx < 3; kx++) {
          float wv = w9[cc * 9 + ky * 3 + kx];
          a0 = fmaf(iv[cc][ky][kx],     wv, a0);
          a1 = fmaf(iv[cc][ky + 1][kx], wv, a1);
        }
    float bz = b1[co0 + co];
    float t0 = a0 + bz, t1 = a1 + bz;
    float s  = wave_sum(t0 + t1);
    float q  = wave_sum(t0 * t0 + t1 * t1);
    if ((tid & 63) == 0) { atomicAdd(&ss[co], s); atomicAdd(&qq[co], q); }
  }
  __syncthreads();
  if (tid < 15) {
    atomicAdd(&S[co0 + tid], ss[tid]);
    atomicAdd(&Q[co0 + tid], qq[tid]);
  }
}

// ---------------- BN finalize ----------------------------------------------
template <int C>
__global__ void bn_finalize(const float* __restrict__ S, const float* __restrict__ Q,
                            const float* __restrict__ g, const float* __restrict__ be,
                            float* __restrict__ A, float* __restrict__ Bs)
{
  int c = threadIdx.x;
  if (c < C) {
    const float invN = 1.f / NHW;
    float m   = S[c] * invN;
    float var = fmaxf(Q[c] * invN - m * m, 0.f);
    float sc  = g[c] * rsqrtf(var + 1e-5f);
    A[c]  = sc;
    Bs[c] = be[c] - m * sc;
  }
}

// ---------------- conv2 MFMA: 256px x 128co, B from global -----------------
// grid (2048): bx -> b, 16x16 px tile. All 128 co per block.
__global__ __launch_bounds__(256, 2) void conv2_mfma(
    const float* __restrict__ X,  const float* __restrict__ w1,
    const float* __restrict__ b1f, const float* __restrict__ A1,
    const float* __restrict__ B1, const unsigned short* __restrict__ W2p,
    const float* __restrict__ b2, unsigned short* __restrict__ t2)
{
  const int bx   = blockIdx.x;
  const int b    = bx >> 4;
  const int t16  = bx & 15;
  const int y0   = (t16 >> 2) * 16;
  const int x0   = (t16 & 3) * 16;
  const int tid  = threadIdx.x;
  const int lane = tid & 63;
  const int wid  = __builtin_amdgcn_readfirstlane(tid >> 6);
  const int ln   = lane & 15;
  const int quad = (lane >> 4) * 8;       // ushort offset within 32-ci chunk

  __shared__ __align__(16) float Xs[2][20][20];
  __shared__ float w1s[2700];
  __shared__ float A1s[150], B1s[150], b1s[150], b2s[128];
  __shared__ __align__(16) unsigned short Atile[324 * 34];   // halo px x ci-chunk
  __shared__ __align__(16) unsigned short outs[256 * 68];    // epilogue buffer

  for (int i = tid; i < 2700; i += 256) w1s[i] = w1[i];
  for (int i = tid; i < 150; i += 256) { A1s[i] = A1[i]; B1s[i] = B1[i]; b1s[i] = b1f[i]; }
  if (tid < 128) b2s[tid] = (tid < 120) ? b2[tid] : 0.f;
  for (int i = tid; i < 800; i += 256) {
    int c2 = i / 400, rem = i - c2 * 400;
    int rr = rem / 20, cc = rem - rr * 20;
    int gy = y0 - 2 + rr, gx = x0 - 2 + cc;
    Xs[c2][rr][cc] = (gy >= 0 && gy < 64 && gx >= 0 && gx < 64)
                         ? X[((size_t)(b * 2 + c2) << 12) + (gy << 6) + gx] : 0.f;
  }

  v4f acc[4][8];
  #pragma unroll
  for (int i = 0; i < 4; i++)
    #pragma unroll
    for (int j = 0; j < 8; j++) acc[i][j] = (v4f){0.f, 0.f, 0.f, 0.f};

  for (int chunk = 0; chunk < 5; chunk++) {
    __syncthreads();                      // prior round's Atile reads done
    {
      // stage A chunk: h1 = relu(bn1(conv1(X))) for ci in [32c, 32c+32)
      const int ci_loc = tid & 31;
      const int ci = chunk * 32 + ci_loc;
      const bool live = (ci < 150);
      float wv[18], sc = 0.f, sh = 0.f, bz = 0.f;
      if (live) {
        #pragma unroll
        for (int k = 0; k < 18; k++) wv[k] = w1s[ci * 18 + k];
        sc = A1s[ci]; sh = B1s[ci]; bz = b1s[ci];
      }
      for (int pass = 0; pass < 41; pass++) {
        int p = pass * 8 + (tid >> 5);
        if (p < 324) {
          float v = 0.f;
          if (live) {
            int pr = p / 18, pc = p - pr * 18;
            int hy = y0 - 1 + pr, hx = x0 - 1 + pc;
            if (hy >= 0 && hy < 64 && hx >= 0 && hx < 64) {
              float a = bz;
              #pragma unroll
              for (int c2 = 0; c2 < 2; c2++)
                #pragma unroll
                for (int ky = 0; ky < 3; ky++)
                  #pragma unroll
                  for (int kx = 0; kx < 3; kx++)
                    a = fmaf(Xs[c2][pr + ky][pc + kx], wv[c2 * 9 + ky * 3 + kx], a);
              v = fmaxf(fmaf(a, sc, sh), 0.f);
            }
          }
          Atile[p * 34 + ci_loc] = f2bf(v);
        }
      }
    }
    __syncthreads();

    // register-cache the 18 distinct A fragments for this round
    v8s afr[6][3];
    #pragma unroll
    for (int t = 0; t < 6; t++)
      #pragma unroll
      for (int kx = 0; kx < 3; kx++)
        afr[t][kx] = *(const v8s*)(&Atile[((wid * 4 + t) * 18 + ln + kx) * 34 + quad]);

    #pragma unroll
    for (int pos = 0; pos < 9; pos++) {
      const int ky = pos / 3, kx = pos - ky * 3;
      // B fragments straight from global (L2-hot): co = nj*16+ln
      const unsigned short* bw =
          W2p + (size_t)(pos * 128 + ln) * 160 + chunk * 32 + quad;
      v8s bf[8];
      #pragma unroll
      for (int nj = 0; nj < 8; nj++)
        bf[nj] = *(const v8s*)(bw + (size_t)nj * 16 * 160);
      #pragma unroll
      for (int mi = 0; mi < 4; mi++) {
        #pragma unroll
        for (int nj = 0; nj < 8; nj++)
          acc[mi][nj] = __builtin_amdgcn_mfma_f32_16x16x32_bf16(
              afr[mi + ky][kx], bf[nj], acc[mi][nj], 0, 0, 0);
      }
    }
  }

  // epilogue: two 64-co halves through outs[256][68], NHWC stores
  #pragma unroll
  for (int half = 0; half < 2; half++) {
    __syncthreads();
    #pragma unroll
    for (int mi = 0; mi < 4; mi++)
      #pragma unroll
      for (int njl = 0; njl < 4; njl++) {
        int n = njl * 16 + ln;
        float bz = b2s[half * 64 + n];
        #pragma unroll
        for (int r2 = 0; r2 < 4; r2++) {
          int m = wid * 64 + mi * 16 + (lane >> 4) * 4 + r2;
          outs[m * 68 + n] = f2bf(acc[mi][half * 4 + njl][r2] + bz);
        }
      }
    __syncthreads();
    const int ng = half ? 7 : 8;     // half1 -> co 64..119 (7 ushort8 groups)
    for (int i = tid; i < 256 * ng; i += 256) {
      int p = i / ng, g = i - p * ng;
      int gy = y0 + (p >> 4), gx = x0 + (p & 15);
      size_t gpx = ((size_t)b << 12) + (gy << 6) + gx;
      *(uint4*)(t2 + gpx * 120 + half * 64 + g * 8) =
          *(const uint4*)(&outs[p * 68 + g * 8]);
    }
  }
}

// ---------------- conv3 MFMA: 256px x 128co, B from global -----------------
__global__ __launch_bounds__(256, 2) void conv3_mfma(
    const unsigned short* __restrict__ t2, const float* __restrict__ A2,
    const float* __restrict__ B2, const unsigned short* __restrict__ W3p,
    const float* __restrict__ b3, unsigned short* __restrict__ t3)
{
  const int bx   = blockIdx.x;
  const int b    = bx >> 4;
  const int t16  = bx & 15;
  const int y0   = (t16 >> 2) * 16;
  const int x0   = (t16 & 3) * 16;
  const int tid  = threadIdx.x;
  const int lane = tid & 63;
  const int wid  = __builtin_amdgcn_readfirstlane(tid >> 6);
  const int ln   = lane & 15;
  const int quad = (lane >> 4) * 8;

  __shared__ float A2s[120], B2s[120], b3s[128];
  __shared__ __align__(16) unsigned short Atile[324 * 34];
  __shared__ __align__(16) unsigned short outs[256 * 68];

  for (int i = tid; i < 120; i += 256) { A2s[i] = A2[i]; B2s[i] = B2[i]; }
  if (tid < 128) b3s[tid] = (tid < 100) ? b3[tid] : 0.f;

  v4f acc[4][8];
  #pragma unroll
  for (int i = 0; i < 4; i++)
    #pragma unroll
    for (int j = 0; j < 8; j++) acc[i][j] = (v4f){0.f, 0.f, 0.f, 0.f};

  for (int chunk = 0; chunk < 4; chunk++) {
    __syncthreads();
    {
      // stage A chunk: BN2+ReLU(t2) halo, ci in [32c, 32c+32)
      const int ci0 = chunk * 32;
      const int ngr = (chunk == 3) ? 3 : 4;    // real uint4 groups (ci<120)
      for (int i = tid; i < 1296; i += 256) {  // 324 px x 4 groups
        int p = i >> 2, g = i & 3;
        int pr = p / 18, pc = p - pr * 18;
        int hy = y0 - 1 + pr, hx = x0 - 1 + pc;
        union { uint4 v; unsigned short u[8]; } ov;
        ov.v = (uint4){0, 0, 0, 0};
        if (g < ngr && hy >= 0 && hy < 64 && hx >= 0 && hx < 64) {
          size_t gpx = ((size_t)b << 12) + (hy << 6) + hx;
          union { uint4 v; unsigned short u[8]; } in;
          in.v = *(const uint4*)(t2 + gpx * 120 + ci0 + g * 8);
          #pragma unroll
          for (int j = 0; j < 8; j++) {
            int ci = ci0 + g * 8 + j;
            ov.u[j] = f2bf(fmaxf(fmaf(bf2f(in.u[j]), A2s[ci], B2s[ci]), 0.f));
          }
        }
        *(uint4*)(&Atile[p * 34 + g * 8]) = ov.v;
      }
    }
    __syncthreads();

    v8s afr[6][3];
    #pragma unroll
    for (int t = 0; t < 6; t++)
      #pragma unroll
      for (int kx = 0; kx < 3; kx++)
        afr[t][kx] = *(const v8s*)(&Atile[((wid * 4 + t) * 18 + ln + kx) * 34 + quad]);

    #pragma unroll
    for (int pos = 0; pos < 9; pos++) {
      const int ky = pos / 3, kx = pos - ky * 3;
      const unsigned short* bw =
          W3p + (size_t)(pos * 128 + ln) * 128 + chunk * 32 + quad;
      v8s bf[8];
      #pragma unroll
      for (int nj = 0; nj < 8; nj++)
        bf[nj] = *(const v8s*)(bw + (size_t)nj * 16 * 128);
      #pragma unroll
      for (int mi = 0; mi < 4; mi++) {
        #pragma unroll
        for (int nj = 0; nj < 8; nj++)
          acc[mi][nj] = __builtin_amdgcn_mfma_f32_16x16x32_bf16(
              afr[mi + ky][kx], bf[nj], acc[mi][nj], 0, 0, 0);
      }
    }
  }

  #pragma unroll
  for (int half = 0; half < 2; half++) {
    __syncthreads();
    #pragma unroll
    for (int mi = 0; mi < 4; mi++)
      #pragma unroll
      for (int njl = 0; njl < 4; njl++) {
        int n = njl * 16 + ln;
        float bz = b3s[half * 64 + n];   // 0 for co>=100 (weights also 0)
        #pragma unroll
        for (int r2 = 0; r2 < 4; r2++) {
          int m = wid * 64 + mi * 16 + (lane >> 4) * 4 + r2;
          outs[m * 68 + n] = f2bf(acc[mi][half * 4 + njl][r2] + bz);
        }
      }
    __syncthreads();
    const int ng = half ? 5 : 8;     // half1 -> co 64..103 (100..103 zeros)
    for (int i = tid; i < 256 * ng; i += 256) {
      int p = i / ng, g = i - p * ng;
      int gy = y0 + (p >> 4), gx = x0 + (p & 15);
      size_t gpx = ((size_t)b << 12) + (gy << 6) + gx;
      *(uint4*)(t3 + gpx * 104 + half * 64 + g * 8) =
          *(const uint4*)(&outs[p * 68 + g * 8]);
    }
  }
}

// ---------------- per-channel sums over NHWC bf16 tensor -------------------
template <int ST, int NG, int C>
__global__ __launch_bounds__(256) void nhwc_stats(
    const unsigned short* __restrict__ t, float* __restrict__ S, float* __restrict__ Q)
{
  const int tid = threadIdx.x;
  const int g   = tid & 15;
  const int pl  = tid >> 4;
  const bool valid = (g < NG);
  const int px0 = blockIdx.x * 512;

  __shared__ float ss[128], qq[128];
  for (int i = tid; i < 128; i += 256) { ss[i] = 0.f; qq[i] = 0.f; }
  __syncthreads();

  float s8[8], q8[8];
  #pragma unroll
  for (int j = 0; j < 8; j++) { s8[j] = 0.f; q8[j] = 0.f; }

  if (valid) {
    for (int it = 0; it < 32; it++) {
      size_t px = px0 + it * 16 + pl;
      union { uint4 v; unsigned short u[8]; } in;
      in.v = *(const uint4*)(t + px * ST + g * 8);
      #pragma unroll
      for (int j = 0; j < 8; j++) {
        float v = bf2f(in.u[j]);
        s8[j] += v;
        q8[j] += v * v;
      }
    }
    #pragma unroll
    for (int j = 0; j < 8; j++) {
      atomicAdd(&ss[g * 8 + j], s8[j]);
      atomicAdd(&qq[g * 8 + j], q8[j]);
    }
  }
  __syncthreads();
  if (tid < C) {
    atomicAdd(&S[tid], ss[tid]);
    atomicAdd(&Q[tid], qq[tid]);
  }
}

// ---------------- BN3+ReLU+1x1 reward reduce over NHWC t3 ------------------
__global__ __launch_bounds__(256) void bn3_reduce_r(
    const unsigned short* __restrict__ t3, const float* __restrict__ A3,
    const float* __restrict__ B3, const float* __restrict__ rw,
    float* __restrict__ r)
{
  __shared__ float A3s[104], B3s[104], rws[104];
  const int tid = threadIdx.x;
  for (int i = tid; i < 104; i += 256) {
    bool v = (i < 100);
    A3s[i] = v ? A3[i] : 0.f;
    B3s[i] = v ? B3[i] : 0.f;
    rws[i] = v ? rw[i] : 0.f;
  }
  __syncthreads();

  size_t px = (size_t)blockIdx.x * 256 + tid;
  const unsigned short* p = t3 + px * 104;
  float a = 0.f;
  #pragma unroll
  for (int gq = 0; gq < 13; gq++) {
    union { uint4 v; unsigned short u[8]; } in;
    in.v = *(const uint4*)(p + gq * 8);
    #pragma unroll
    for (int j = 0; j < 8; j++) {
      int ci = gq * 8 + j;
      a = fmaf(fmaxf(fmaf(bf2f(in.u[j]), A3s[ci], B3s[ci]), 0.f), rws[ci], a);
    }
  }
  r[px] = a;
}

// ---------------- qr = conv5x5(r, q_w); v0 = max_a qr ----------------------
__global__ __launch_bounds__(256) void qr_init(
    const float* __restrict__ r, const float* __restrict__ qw,
    float* __restrict__ qr, float* __restrict__ v0)
{
  const int tile = blockIdx.x;          // 128*16
  const int b    = tile >> 4;
  const int y0t  = (tile & 15) * 4;
  const int tid  = threadIdx.x;
  const int x    = tid & 63;
  const int ly   = tid >> 6;

  __shared__ float lv[8][68];
  for (int idx = tid; idx < 8 * 68; idx += 256) {
    int rr = idx / 68, c = idx - rr * 68;
    int yy = y0t + rr - 2, xx = c - 2;
    lv[rr][c] = (yy >= 0 && yy < 64 && xx >= 0 && xx < 64)
                    ? r[((size_t)b << 12) + (yy << 6) + xx] : 0.f;
  }
  __syncthreads();

  float iv[5][5];
  #pragma unroll
  for (int ky = 0; ky < 5; ky++)
    #pragma unroll
    for (int kx = 0; kx < 5; kx++) iv[ky][kx] = lv[ly + ky][x + kx];

  const int y = y0t + ly;
  float vmax = -1e30f;
  #pragma unroll
  for (int a = 0; a < 10; a++) {
    float q = 0.f;
    #pragma unroll
    for (int ky = 0; ky < 5; ky++)
      #pragma unroll
      for (int kx = 0; kx < 5; kx++)
        q = fmaf(iv[ky][kx], qw[a * 25 + ky * 5 + kx], q);
    qr[((size_t)(b * 10 + a) << 12) + (y << 6) + x] = q;
    vmax = fmaxf(vmax, q);
  }
  v0[((size_t)b << 12) + (y << 6) + x] = vmax;
}

// ---------------- VI step: v' = max_a (qr + conv5x5(v, w)) -----------------
__global__ __launch_bounds__(256) void vi_step(
    const float* __restrict__ vin, const float* __restrict__ qr,
    const float* __restrict__ ww, float* __restrict__ vout)
{
  const int tile = blockIdx.x;
  const int b    = tile >> 4;
  const int y0t  = (tile & 15) * 4;
  const int tid  = threadIdx.x;
  const int x    = tid & 63;
  const int ly   = tid >> 6;

  __shared__ float lv[8][68];
  for (int idx = tid; idx < 8 * 68; idx += 256) {
    int rr = idx / 68, c = idx - rr * 68;
    int yy = y0t + rr - 2, xx = c - 2;
    lv[rr][c] = (yy >= 0 && yy < 64 && xx >= 0 && xx < 64)
                    ? vin[((size_t)b << 12) + (yy << 6) + xx] : 0.f;
  }
  __syncthreads();

  float iv[5][5];
  #pragma unroll
  for (int ky = 0; ky < 5; ky++)
    #pragma unroll
    for (int kx = 0; kx < 5; kx++) iv[ky][kx] = lv[ly + ky][x + kx];

  const int y = y0t + ly;
  float vmax = -1e30f;
  #pragma unroll
  for (int a = 0; a < 10; a++) {
    float q = qr[((size_t)(b * 10 + a) << 12) + (y << 6) + x];
    #pragma unroll
    for (int ky = 0; ky < 5; ky++)
      #pragma unroll
      for (int kx = 0; kx < 5; kx++)
        q = fmaf(iv[ky][kx], ww[a * 25 + ky * 5 + kx], q);
    vmax = fmaxf(vmax, q);
  }
  vout[((size_t)b << 12) + (y << 6) + x] = vmax;
}

// ---------------- critic ---------------------------------------------------
__global__ __launch_bounds__(256) void critic_k(
    const float* __restrict__ v, const float* __restrict__ cvw,
    const float* __restrict__ cvb, float* __restrict__ out)
{
  const int b = blockIdx.x;
  const int tid = threadIdx.x;
  const float4* pv = (const float4*)(v + ((size_t)b << 12));
  const float4* pw = (const float4*)cvw;
  float s = 0.f;
  #pragma unroll
  for (int i = 0; i < 4; i++) {
    float4 a = pv[tid + 256 * i];
    float4 w = pw[tid + 256 * i];
    s += a.x * w.x + a.y * w.y + a.z * w.z + a.w * w.w;
  }
  s = wave_sum(s);
  __shared__ float ls[4];
  const int w = tid >> 6;
  if ((tid & 63) == 0) ls[w] = s;
  __syncthreads();
  if (tid == 0) out[b] = ls[0] + ls[1] + ls[2] + ls[3] + cvb[0];
}

// ---------------- action MLP ----------------------------------------------
__global__ __launch_bounds__(128) void action_k(
    const float* __restrict__ obs, const float* __restrict__ fc1w,
    const float* __restrict__ fc1b, const float* __restrict__ fc2w,
    const float* __restrict__ fc2b, float* __restrict__ out)
{
  const int b = blockIdx.x;
  const int j = threadIdx.x;
  __shared__ float ob[24];
  __shared__ float h[100];
  if (j < 24) ob[j] = obs[b * 24 + j];
  __syncthreads();
  if (j < 100) {
    float s = fc1b[j];
    #pragma unroll
    for (int k = 0; k < 24; k++) s = fmaf(ob[k], fc1w[j * 24 + k], s);
    h[j] = fmaxf(s, 0.f);
  }
  __syncthreads();
  if (j < 10) {
    float s = fc2b[j];
    for (int k = 0; k < 100; k++) s = fmaf(h[k], fc2w[j * 100 + k], s);
    out[128 + b * 10 + j] = fmaxf(s, 0.f);
  }
}

// ---------------------------------------------------------------------------
extern "C" void kernel_launch(void* const* d_in, const int* in_sizes, int n_in,
                              void* d_out, int out_size, void* d_ws,
                              size_t ws_size, hipStream_t stream)
{
  const float* X     = (const float*)d_in[0];
  const float* obs   = (const float*)d_in[1];
  const float* h1_w  = (const float*)d_in[2];
  const float* h1_b  = (const float*)d_in[3];
  const float* g1    = (const float*)d_in[4];
  const float* b1    = (const float*)d_in[5];
  const float* h2_w  = (const float*)d_in[6];
  const float* h2_b  = (const float*)d_in[7];
  const float* g2    = (const float*)d_in[8];
  const float* b2    = (const float*)d_in[9];
  const float* h3_w  = (const float*)d_in[10];
  const float* h3_b  = (const float*)d_in[11];
  const float* g3    = (const float*)d_in[12];
  const float* b3    = (const float*)d_in[13];
  const float* r_w   = (const float*)d_in[14];
  const float* q_w   = (const float*)d_in[15];
  const float* w_vi  = (const float*)d_in[16];
  const float* fc1_w = (const float*)d_in[17];
  const float* fc1_b = (const float*)d_in[18];
  const float* fc2_w = (const float*)d_in[19];
  const float* fc2_b = (const float*)d_in[20];
  const float* cv_w  = (const float*)d_in[21];
  const float* cv_b  = (const float*)d_in[22];
  // K (d_in[23]) fixed to 36 by setup; loop count is compile-time.

  char* ws = (char*)d_ws;
  unsigned short* t2  = (unsigned short*)ws;                       // 125,829,120 B
  unsigned short* t3  = (unsigned short*)(ws + 125829120ull);      // 109,051,904 B
  unsigned short* W2p = (unsigned short*)(ws + 234881024ull);      //     368,640 B
  unsigned short* W3p = (unsigned short*)(ws + 235249664ull);      //     294,912 B
  float*          ST  = (float*)         (ws + 235544576ull);      //       5,920 B
  float* S1 = ST +    0; float* Q1 = ST +  150; float* A1 = ST +  300; float* B1 = ST +  450;
  float* S2 = ST +  600; float* Q2 = ST +  720; float* A2 = ST +  840; float* B2 = ST +  960;
  float* S3 = ST + 1080; float* Q3 = ST + 1180; float* A3 = ST + 1280; float* B3 = ST + 1380;
  // VI fp32 buffers aliased over dead t2 region
  float* r  = (float*)ws;          // 524,288 f
  float* qr = r + 524288;          // 5,242,880 f
  float* vA = qr + 5242880;        // 524,288 f
  float* vB = vA + 524288;         // 524,288 f

  hipMemsetAsync(ST, 0, 1480 * sizeof(float), stream);

  repack_w<120, 150, 160><<<720, 256, 0, stream>>>(h2_w, W2p);
  repack_w<100, 120, 128><<<576, 256, 0, stream>>>(h3_w, W3p);

  conv1_stats<<<dim3(1024, 10), 256, 0, stream>>>(X, h1_w, h1_b, S1, Q1);
  bn_finalize<150><<<1, 256, 0, stream>>>(S1, Q1, g1, b1, A1, B1);

  conv2_mfma<<<2048, 256, 0, stream>>>(X, h1_w, h1_b, A1, B1, W2p, h2_b, t2);
  nhwc_stats<120, 15, 120><<<1024, 256, 0, stream>>>(t2, S2, Q2);
  bn_finalize<120><<<1, 256, 0, stream>>>(S2, Q2, g2, b2, A2, B2);

  conv3_mfma<<<2048, 256, 0, stream>>>(t2, A2, B2, W3p, h3_b, t3);
  nhwc_stats<104, 13, 100><<<1024, 256, 0, stream>>>(t3, S3, Q3);
  bn_finalize<100><<<1, 256, 0, stream>>>(S3, Q3, g3, b3, A3, B3);

  bn3_reduce_r<<<2048, 256, 0, stream>>>(t3, A3, B3, r_w, r);

  qr_init<<<2048, 256, 0, stream>>>(r, q_w, qr, vA);
  for (int i = 0; i < 36; i++) {
    const float* vin = (i & 1) ? vB : vA;
    float* vout      = (i & 1) ? vA : vB;
    vi_step<<<2048, 256, 0, stream>>>(vin, qr, w_vi, vout);
  }

  float* out = (float*)d_out;
  critic_k<<<128, 256, 0, stream>>>(vA, cv_w, cv_b, out);
  action_k<<<128, 128, 0, stream>>>(obs, fc1_w, fc1_b, fc2_w, fc2_b, out);
}